// Round 6
// baseline (939.444 us; speedup 1.0000x reference)
//
#include <hip/hip_runtime.h>
#include <cfloat>
#include <math.h>

#define D_DIM 1024
#define B_DIM 4
#define NQ    1024
#define NC    16384
#define TOPN  5
#define TOPA  5               // stage-A candidates per context split
#define CSPLIT 8              // context splits per batch
#define CAND  (TOPA*CSPLIT)   // 40 candidates per query
#define QT    64              // queries per block (dist kernel)
#define CTILE 256             // contexts per tile iteration (dist kernel)
#define BK    64              // K per LDS stage (bf16 elements)
#define NSTEP (D_DIM/BK)      // 16 K-steps

// proj (fp64 MFMA) tiling
#define PBM 128
#define PBN 64
#define PBK 16
#define PPAD 4   // row stride 20 floats = 80 B = 5x16 -> float4 LDS stores stay 16B-aligned
#define PROJ_BLKS ((D_DIM/PBN) * ((B_DIM*NQ)/PBM))   // 512

typedef __bf16 bf16x8 __attribute__((ext_vector_type(8)));
typedef float  f32x4  __attribute__((ext_vector_type(4)));
typedef double f64x4  __attribute__((ext_vector_type(4)));

__device__ __forceinline__ unsigned short f2bf(float f) {
    unsigned u = __builtin_bit_cast(unsigned, f);
    unsigned r = (u + 0x7fffu + ((u >> 16) & 1u)) >> 16;
    return (unsigned short)r;
}

// async global->LDS, 16B per lane; LDS dest = wave-uniform base + lane*16
__device__ __forceinline__ void gload16(const void* g, void* l) {
    __builtin_amdgcn_global_load_lds(
        (const __attribute__((address_space(1))) unsigned*)g,
        (__attribute__((address_space(3))) unsigned*)l, 16, 0, 0);
}

// ---- lexicographic (value, index) top-N insert (used by fp64 refine) ----
template<int N, typename T>
__device__ __forceinline__ void topk_insert(T (&bv)[N], int (&bi)[N], T v, int ci) {
    if (v < bv[N-1] || (v == bv[N-1] && ci < bi[N-1])) {
        bv[N-1] = v; bi[N-1] = ci;
        #pragma unroll
        for (int s = N-1; s > 0; --s) {
            bool sw = (bv[s] < bv[s-1]) || (bv[s] == bv[s-1] && bi[s] < bi[s-1]);
            if (sw) {
                T tv = bv[s-1]; bv[s-1] = bv[s]; bv[s] = tv;
                int ti = bi[s-1]; bi[s-1] = bi[s]; bi[s] = ti;
            }
        }
    }
}

// ---- value-only top-N insert (merge phases; ties resolved by fp64 refine) ----
template<int N>
__device__ __forceinline__ void insN(float (&bv)[N], int (&bi)[N], float v, int ci) {
    if (v < bv[N-1]) {
        bv[N-1] = v; bi[N-1] = ci;
        #pragma unroll
        for (int s = N-1; s > 0; --s) {
            if (bv[s] < bv[s-1]) {
                float tv = bv[s-1]; bv[s-1] = bv[s]; bv[s] = tv;
                int   ti = bi[s-1]; bi[s-1] = bi[s]; bi[s] = ti;
            }
        }
    }
}

// ---- branchless sorted (value,index) top-5 insert for the hot acc drain ----
__device__ __forceinline__ void ins5b(float (&bv)[TOPA], int (&bi)[TOPA], float v, int ci) {
    #pragma unroll
    for (int s = 0; s < TOPA; ++s) {
        const bool  c    = v < bv[s];
        const float vmin = c ? v : bv[s];
        const float vmax = c ? bv[s] : v;
        const int   imin = c ? ci : bi[s];
        const int   imax = c ? bi[s] : ci;
        bv[s] = vmin; bi[s] = imin;
        v = vmax; ci = imax;
    }
}

// ---- Kernel 1 (fat): blocks [0,512) = fp64-MFMA projection; rest = pack C ----
// proj: 128x64 tile, 4 waves 2x2, wave 64x32 (4x2 frags of 16x16).
// v_mfma_f64_16x16x4_f64: A row=l&15,k=l>>4; B col=l&15,k=l>>4; D row=4*reg+(l>>4).
// pack_c is HBM-bound, proj is f64-pipe-bound -> co-resident blocks overlap free.
__global__ __launch_bounds__(256) void proj_packc_kernel(const float* __restrict__ Q,
                                                         const float* __restrict__ W,
                                                         const float* __restrict__ bias,
                                                         const float* __restrict__ C,
                                                         double* __restrict__ P64,
                                                         unsigned short* __restrict__ Cbf,
                                                         float* __restrict__ csq)
{
    const int bid = blockIdx.x;
    if (bid >= PROJ_BLKS) {
        // ---------------- pack_c branch ----------------
        int wave = threadIdx.x >> 6;
        int lane = threadIdx.x & 63;
        int row  = (bid - PROJ_BLKS) * 4 + wave;
        const float* x = C + (size_t)row * D_DIM;
        float s = 0.f;
        #pragma unroll
        for (int i = 0; i < 4; ++i) {
            float4 v = *(const float4*)&x[lane * 4 + i * 256];
            s += v.x * v.x + v.y * v.y + v.z * v.z + v.w * v.w;
            ushort4 h;
            h.x = f2bf(v.x); h.y = f2bf(v.y); h.z = f2bf(v.z); h.w = f2bf(v.w);
            *(ushort4*)&Cbf[(size_t)row * D_DIM + lane * 4 + i * 256] = h;
        }
        #pragma unroll
        for (int off = 32; off; off >>= 1) s += __shfl_down(s, off, 64);
        if (lane == 0) csq[row] = s;
        return;
    }
    // ---------------- proj branch ----------------
    __shared__ float Qs[PBM][PBK + PPAD];
    __shared__ float Ws[PBN][PBK + PPAD];

    const int t    = threadIdx.x;
    const int lane = t & 63;
    const int w    = t >> 6;          // wave 0..3
    const int l15  = lane & 15;
    const int l4   = lane >> 4;       // 0..3
    const int m0   = (bid >> 4) * PBM;
    const int n0   = (bid & 15) * PBN;
    const int wm   = (w >> 1) * 64;   // wave row offset in tile
    const int wn   = (w & 1) * 32;    // wave col offset in tile

    const int srow = t >> 2;          // 0..63 staging row
    const int scol = (t & 3) * 4;     // staging float4 col

    f64x4 acc[4][2];
    #pragma unroll
    for (int fm = 0; fm < 4; ++fm)
        #pragma unroll
        for (int fn = 0; fn < 2; ++fn) acc[fm][fn] = (f64x4)0.0;

    for (int k0 = 0; k0 < D_DIM; k0 += PBK) {
        float4 qa0 = *(const float4*)&Q[(size_t)(m0 + srow)      * D_DIM + k0 + scol];
        float4 qa1 = *(const float4*)&Q[(size_t)(m0 + srow + 64) * D_DIM + k0 + scol];
        float4 wa  = *(const float4*)&W[(size_t)(n0 + srow)      * D_DIM + k0 + scol];
        __syncthreads();   // previous-iteration readers done
        *(float4*)&Qs[srow][scol]      = qa0;
        *(float4*)&Qs[srow + 64][scol] = qa1;
        *(float4*)&Ws[srow][scol]      = wa;
        __syncthreads();   // tile visible to all waves

        #pragma unroll
        for (int ks = 0; ks < 4; ++ks) {
            const int kc = ks * 4 + l4;
            double a[4], b[2];
            #pragma unroll
            for (int fm = 0; fm < 4; ++fm) a[fm] = (double)Qs[wm + fm * 16 + l15][kc];
            #pragma unroll
            for (int fn = 0; fn < 2; ++fn) b[fn] = (double)Ws[wn + fn * 16 + l15][kc];
            #pragma unroll
            for (int fm = 0; fm < 4; ++fm)
                #pragma unroll
                for (int fn = 0; fn < 2; ++fn)
                    acc[fm][fn] = __builtin_amdgcn_mfma_f64_16x16x4f64(a[fm], b[fn], acc[fm][fn], 0, 0, 0);
        }
    }

    #pragma unroll
    for (int fm = 0; fm < 4; ++fm) {
        #pragma unroll
        for (int fn = 0; fn < 2; ++fn) {
            const int col = n0 + wn + fn * 16 + l15;
            const double bv = (double)bias[col];
            #pragma unroll
            for (int j = 0; j < 4; ++j) {
                const int row = m0 + wm + fm * 16 + j * 4 + l4;   // f64 shape: reg strides 4 rows
                P64[(size_t)row * D_DIM + col] = acc[fm][fn][j] + bv;
            }
        }
    }
}

// ---- Kernel 1b: measure the actual within-16 row permutation of P64 ----
__global__ __launch_bounds__(256) void perm_detect_kernel(const float* __restrict__ Q,
                                                          const float* __restrict__ W,
                                                          const float* __restrict__ bias,
                                                          const double* __restrict__ P64,
                                                          int* __restrict__ invperm)
{
    __shared__ double tv[16];
    const int t = threadIdx.x;      // 256 threads
    const int g = t >> 4;           // true row 0..15
    const int s = t & 15;           // k-slice
    if (t < 16) invperm[t] = t;     // identity default (overwritten below)

    double acc = 0.0;
    const int kb = s * 64;
    for (int k = 0; k < 64; ++k)
        acc = fma((double)Q[(size_t)g * D_DIM + kb + k], (double)W[kb + k], acc);
    #pragma unroll
    for (int off = 8; off; off >>= 1) acc += __shfl_down(acc, off, 16);
    if (s == 0) tv[g] = acc + (double)bias[0];
    __syncthreads();

    if (t < 16) {
        double p = P64[(size_t)t * D_DIM];   // physical row t, col 0
        int best = 0; double bd = fabs(p - tv[0]);
        #pragma unroll
        for (int i = 1; i < 16; ++i) {
            double d = fabs(p - tv[i]);
            if (d < bd) { bd = d; best = i; }
        }
        invperm[best] = t;   // physical row t holds true row `best`
    }
}

// ---- Kernel 3: pack P64 -> bf16 Pbf + fp32 qsq (reads physical rows via invperm) ----
__global__ __launch_bounds__(256) void pack_q_kernel(const double* __restrict__ P64,
                                                     const int* __restrict__ invperm,
                                                     unsigned short* __restrict__ Pbf,
                                                     float* __restrict__ qsq)
{
    int wave = threadIdx.x >> 6;
    int lane = threadIdx.x & 63;
    int row  = blockIdx.x * 4 + wave;                 // true row
    int prow = (row & ~15) | invperm[row & 15];       // physical row in P64
    const double* x = P64 + (size_t)prow * D_DIM;
    float s = 0.f;
    #pragma unroll
    for (int j = 0; j < 8; ++j) {
        double2 v = *(const double2*)&x[lane * 2 + j * 128];
        float a = (float)v.x, b = (float)v.y;
        s += a * a + b * b;
        ushort2 h; h.x = f2bf(a); h.y = f2bf(b);
        *(ushort2*)&Pbf[(size_t)row * D_DIM + lane * 2 + j * 128] = h;
    }
    #pragma unroll
    for (int off = 32; off; off >>= 1) s += __shfl_down(s, off, 64);
    if (lane == 0) qsq[row] = s;
}

// ---- Kernel 4: bf16-MFMA screening GEMM + per-lane register top-5 ----
// grid: (CSPLIT, NQ/QT, B), block 256 = 4 waves. Block tile: 64 q x 256 c/iter.
// R6: C fragments load GLOBAL->REGISTER (no LDS round-trip: each C quarter was
// read by exactly one wave, and the fragment pattern is 64B-line coalesced).
// Only Q (shared 4x across waves) stays in LDS, double-buffered (16 KB), ONE
// barrier per K-step. C-frags + next Q-tile prefetched one step ahead into
// static cfA/cfB register sets (rule #20). Numerics bit-identical to R5.
__global__ __launch_bounds__(256, 2) void dist_mfma_kernel(const unsigned short* __restrict__ Pbf,
                                                           const unsigned short* __restrict__ Cbf,
                                                           const float* __restrict__ qsq,
                                                           const float* __restrict__ csq,
                                                           int* __restrict__ pi)
{
    __shared__ __align__(16) short QsS[2][QT * 64];   // 16 KB Q double-buffer
    __shared__ float MVs[QT * 4 * TOPA];              // 5 KB merge values
    __shared__ int   MIs[QT * 4 * TOPA];              // 5 KB merge indices

    const int t    = threadIdx.x;
    const int lane = t & 63;
    const int w    = t >> 6;       // wave 0..3 -> context quarter
    const int l15  = lane & 15;
    const int l4   = lane >> 4;    // 0..3
    const int r8   = lane >> 3;    // 0..7 (Q staging sub-row)
    const int sc   = lane & 7;     // Q staging store-chunk
    const int csplit = blockIdx.x;
    const int by = blockIdx.y;
    const int bz = blockIdx.z;
    const int qg0 = bz * NQ + by * QT;
    const int cpb = NC / CSPLIT;   // 2048
    const int cgb = csplit * cpb;  // context group base within batch
    const int nIt = cpb / CTILE;   // 8

    // Q staging lane offsets (source-side XOR swizzle; unchanged from R5)
    unsigned qOff[2];
    #pragma unroll
    for (int j = 0; j < 2; ++j)
        qOff[j] = (unsigned)((w * 16 + j * 8 + r8) * D_DIM + (sc ^ r8) * 8);
    const unsigned short* qBase = Pbf + (size_t)qg0 * D_DIM;

    // C fragment lane k-offsets: chunk (ks*4+l4), 8 bf16 each
    int koff[2];
    #pragma unroll
    for (int ks = 0; ks < 2; ++ks) koff[ks] = (ks * 4 + l4) * 8;

    float qsv[4];
    #pragma unroll
    for (int s = 0; s < 4; ++s) qsv[s] = qsq[qg0 + s * 16 + l15];

    float bv[4][TOPA]; int bi[4][TOPA];
    #pragma unroll
    for (int s = 0; s < 4; ++s)
        #pragma unroll
        for (int j = 0; j < TOPA; ++j) { bv[s][j] = FLT_MAX; bi[s][j] = 0x7fffffff; }

    f32x4 acc[4][4];
    bf16x8 cfA[2][4], cfB[2][4];

    auto stageQ = [&](int k0, int buf) {
        const unsigned short* qB = qBase + k0;
        #pragma unroll
        for (int j = 0; j < 2; ++j)
            gload16(qB + qOff[j], &QsS[buf][(w * 16 + j * 8) * 64]);
    };
    auto loadC = [&](int itx, int k0, bf16x8 (&cf)[2][4]) {
        const size_t rb = ((size_t)bz * NC + cgb + itx * CTILE + w * 64 + l15) * D_DIM + k0;
        #pragma unroll
        for (int ks = 0; ks < 2; ++ks)
            #pragma unroll
            for (int u = 0; u < 4; ++u)
                cf[ks][u] = *(const bf16x8*)&Cbf[rb + (size_t)(u * 16) * D_DIM + koff[ks]];
    };
    auto compute = [&](const bf16x8 (&cf)[2][4], int qb) {
        #pragma unroll
        for (int ks = 0; ks < 2; ++ks) {
            const int sp = ((ks * 4 + l4) ^ (l15 & 7)) * 8;
            bf16x8 bq[4];
            #pragma unroll
            for (int s = 0; s < 4; ++s)
                bq[s] = *(const bf16x8*)&QsS[qb][(s * 16 + l15) * 64 + sp];
            #pragma unroll
            for (int u = 0; u < 4; ++u)
                #pragma unroll
                for (int s = 0; s < 4; ++s)
                    acc[u][s] = __builtin_amdgcn_mfma_f32_16x16x32_bf16(cf[ks][u], bq[s], acc[u][s], 0, 0, 0);
        }
    };

    // pipeline prologue: first Q tile + first C fragments
    stageQ(0, 0);
    loadC(0, 0, cfA);
    __syncthreads();

    for (int it = 0; it < nIt; ++it) {
        const int cg0 = cgb + it * CTILE;
        #pragma unroll
        for (int u = 0; u < 4; ++u)
            #pragma unroll
            for (int s = 0; s < 4; ++s) acc[u][s] = (f32x4)0.0f;

        for (int kk = 0; kk < NSTEP; kk += 2) {
            // even step: compute cfA / Qbuf0; prefetch (kk+1) into cfB / Qbuf1
            stageQ((kk + 1) * BK, 1);
            loadC(it, (kk + 1) * BK, cfB);
            compute(cfA, 0);
            __syncthreads();

            // odd step: compute cfB / Qbuf1; prefetch (kk+2 | next it) into cfA / Qbuf0
            if (kk < NSTEP - 2) {
                stageQ((kk + 2) * BK, 0);
                loadC(it, (kk + 2) * BK, cfA);
            } else if (it + 1 < nIt) {
                stageQ(0, 0);
                loadC(it + 1, 0, cfA);
            }
            compute(cfB, 1);
            __syncthreads();
        }

        // d^2 = |q|^2 + |c|^2 - 2 q.c  -> branchless per-lane register top-5
        #pragma unroll
        for (int u = 0; u < 4; ++u) {
            const int crow = w * 64 + u * 16 + l4 * 4;
            float4 cs4 = *(const float4*)&csq[(size_t)bz * NC + cg0 + crow];
            float csa[4] = {cs4.x, cs4.y, cs4.z, cs4.w};
            #pragma unroll
            for (int s = 0; s < 4; ++s) {
                #pragma unroll
                for (int r = 0; r < 4; ++r) {
                    float v = qsv[s] + csa[r] - 2.0f * acc[u][s][r];
                    ins5b(bv[s], bi[s], v, cg0 + crow + r);
                }
            }
        }
    }

    // wave-level merge across l4 groups (same query columns) via shuffles
    #pragma unroll
    for (int mask = 16; mask <= 32; mask <<= 1) {
        #pragma unroll
        for (int s = 0; s < 4; ++s) {
            float ov[TOPA]; int oi[TOPA];
            #pragma unroll
            for (int j = 0; j < TOPA; ++j) {
                ov[j] = __shfl_xor(bv[s][j], mask, 64);
                oi[j] = __shfl_xor(bi[s][j], mask, 64);
            }
            #pragma unroll
            for (int j = 0; j < TOPA; ++j) insN<TOPA>(bv[s], bi[s], ov[j], oi[j]);
        }
    }
    // cross-wave merge via LDS (l4==0 lanes hold wave-merged lists)
    __syncthreads();
    if (l4 == 0) {
        #pragma unroll
        for (int s = 0; s < 4; ++s) {
            int q = s * 16 + l15;
            #pragma unroll
            for (int j = 0; j < TOPA; ++j) {
                MVs[(q * 4 + w) * TOPA + j] = bv[s][j];
                MIs[(q * 4 + w) * TOPA + j] = bi[s][j];
            }
        }
    }
    __syncthreads();
    if (t < QT) {
        float mv[TOPA]; int mi[TOPA];
        #pragma unroll
        for (int j = 0; j < TOPA; ++j) { mv[j] = FLT_MAX; mi[j] = 0x7fffffff; }
        for (int l = 0; l < 4; ++l)
            #pragma unroll
            for (int j = 0; j < TOPA; ++j)
                insN<TOPA>(mv, mi, MVs[(t * 4 + l) * TOPA + j], MIs[(t * 4 + l) * TOPA + j]);
        size_t base = (((size_t)qg0 + t) * CSPLIT + csplit) * TOPA;
        #pragma unroll
        for (int j = 0; j < TOPA; ++j) pi[base + j] = mi[j];
    }
}

// ---- Kernel 5: fp64 exact refine of 40 candidates per query -> top-5, sqrt, outputs ----
__global__ __launch_bounds__(256) void refine_kernel(const double* __restrict__ P64,
                                                     const int* __restrict__ invperm,
                                                     const float* __restrict__ C,
                                                     const int*   __restrict__ pi,
                                                     float* __restrict__ out)
{
    __shared__ double dvs[CAND];
    __shared__ int    dis[CAND];
    const int q    = blockIdx.x;                      // true row
    const int pq   = (q & ~15) | invperm[q & 15];     // physical row in P64
    const int bz   = q >> 10;
    const int t    = threadIdx.x;
    const int wave = t >> 6;
    const int lane = t & 63;
    const double* p = P64 + (size_t)pq * D_DIM;

    for (int k = wave; k < CAND; k += 4) {
        int ci = pi[(size_t)q * CAND + k];
        const float* c = C + ((size_t)bz * NC + ci) * D_DIM;
        double s = 0.0;
        #pragma unroll
        for (int j = 0; j < 16; ++j) {
            int d = lane + 64 * j;
            double diff = p[d] - (double)c[d];
            s = fma(diff, diff, s);
        }
        #pragma unroll
        for (int off = 32; off; off >>= 1) s += __shfl_down(s, off, 64);
        if (lane == 0) { dvs[k] = s; dis[k] = ci; }
    }
    __syncthreads();
    if (t == 0) {
        double bv[TOPN]; int bi[TOPN];
        #pragma unroll
        for (int j = 0; j < TOPN; ++j) { bv[j] = DBL_MAX; bi[j] = 0x7fffffff; }
        for (int k = 0; k < CAND; ++k)
            topk_insert<TOPN,double>(bv, bi, dvs[k], dis[k]);
        #pragma unroll
        for (int j = 0; j < TOPN; ++j) {
            out[(size_t)q * TOPN + j] = (float)sqrt(bv[j]);
            out[(size_t)B_DIM * NQ * TOPN + (size_t)q * TOPN + j] = (float)bi[j];
        }
    }
}

extern "C" void kernel_launch(void* const* d_in, const int* in_sizes, int n_in,
                              void* d_out, int out_size, void* d_ws, size_t ws_size,
                              hipStream_t stream) {
    const float* Q    = (const float*)d_in[0];
    const float* C    = (const float*)d_in[1];
    const float* W    = (const float*)d_in[2];
    const float* bias = (const float*)d_in[3];
    float* out = (float*)d_out;

    char* ws = (char*)d_ws;
    double*         P64 = (double*)ws;                                       // 32 MB
    unsigned short* Pbf = (unsigned short*)(ws + (size_t)32 * 1024 * 1024);  //  8 MB
    unsigned short* Cbf = (unsigned short*)(ws + (size_t)40 * 1024 * 1024);  // 128 MB
    float*          qsq = (float*)(ws + (size_t)168 * 1024 * 1024);          // 16 KB
    float*          csq = qsq + 4096;                                        // 256 KB
    int*            pi  = (int*)(csq + 65536);                               // 655 KB
    int*            ivp = pi + (size_t)B_DIM * NQ * CAND;                    // 64 B
    // total ~170 MB of workspace

    proj_packc_kernel<<<PROJ_BLKS + (B_DIM * NC) / 4, 256, 0, stream>>>(Q, W, bias, C, P64, Cbf, csq);
    perm_detect_kernel<<<1, 256, 0, stream>>>(Q, W, bias, P64, ivp);
    pack_q_kernel<<<(B_DIM * NQ) / 4, 256, 0, stream>>>(P64, ivp, Pbf, qsq);
    dist_mfma_kernel<<<dim3(CSPLIT, NQ / QT, B_DIM), 256, 0, stream>>>(Pbf, Cbf, qsq, csq, pi);
    refine_kernel<<<B_DIM * NQ, 256, 0, stream>>>(P64, ivp, C, pi, out);
}

// Round 7
// 915.863 us; speedup vs baseline: 1.0257x; 1.0257x over previous
//
#include <hip/hip_runtime.h>
#include <cfloat>
#include <math.h>

#define D_DIM 1024
#define B_DIM 4
#define NQ    1024
#define NC    16384
#define TOPN  5
#define TOPA  5               // stage-A candidates per context split
#define CSPLIT 8              // context splits per batch
#define CAND  (TOPA*CSPLIT)   // 40 candidates per query
#define QT    128             // queries per block (R7: 64->128, halves C re-reads)
#define CTILE 256             // contexts per tile iteration (dist kernel)
#define BK    64              // K per LDS stage (bf16 elements)

// proj (fp64 MFMA) tiling
#define PBM 128
#define PBN 64
#define PBK 16
#define PPAD 4   // row stride 20 floats = 80 B = 5x16 -> float4 LDS stores stay 16B-aligned
#define PROJ_BLKS ((D_DIM/PBN) * ((B_DIM*NQ)/PBM))   // 512

typedef __bf16 bf16x8 __attribute__((ext_vector_type(8)));
typedef float  f32x4  __attribute__((ext_vector_type(4)));
typedef double f64x4  __attribute__((ext_vector_type(4)));

__device__ __forceinline__ unsigned short f2bf(float f) {
    unsigned u = __builtin_bit_cast(unsigned, f);
    unsigned r = (u + 0x7fffu + ((u >> 16) & 1u)) >> 16;
    return (unsigned short)r;
}

// async global->LDS, 16B per lane; LDS dest = wave-uniform base + lane*16
__device__ __forceinline__ void gload16(const void* g, void* l) {
    __builtin_amdgcn_global_load_lds(
        (const __attribute__((address_space(1))) unsigned*)g,
        (__attribute__((address_space(3))) unsigned*)l, 16, 0, 0);
}

// ---- lexicographic (value, index) top-N insert (used by fp64 refine) ----
template<int N, typename T>
__device__ __forceinline__ void topk_insert(T (&bv)[N], int (&bi)[N], T v, int ci) {
    if (v < bv[N-1] || (v == bv[N-1] && ci < bi[N-1])) {
        bv[N-1] = v; bi[N-1] = ci;
        #pragma unroll
        for (int s = N-1; s > 0; --s) {
            bool sw = (bv[s] < bv[s-1]) || (bv[s] == bv[s-1] && bi[s] < bi[s-1]);
            if (sw) {
                T tv = bv[s-1]; bv[s-1] = bv[s]; bv[s] = tv;
                int ti = bi[s-1]; bi[s-1] = bi[s]; bi[s] = ti;
            }
        }
    }
}

// ---- value-only top-N insert (merge phases; ties resolved by fp64 refine) ----
template<int N>
__device__ __forceinline__ void insN(float (&bv)[N], int (&bi)[N], float v, int ci) {
    if (v < bv[N-1]) {
        bv[N-1] = v; bi[N-1] = ci;
        #pragma unroll
        for (int s = N-1; s > 0; --s) {
            if (bv[s] < bv[s-1]) {
                float tv = bv[s-1]; bv[s-1] = bv[s]; bv[s] = tv;
                int   ti = bi[s-1]; bi[s-1] = bi[s]; bi[s] = ti;
            }
        }
    }
}

// ---- branchless sorted (value,index) top-5 insert for the hot acc drain ----
__device__ __forceinline__ void ins5b(float (&bv)[TOPA], int (&bi)[TOPA], float v, int ci) {
    #pragma unroll
    for (int s = 0; s < TOPA; ++s) {
        const bool  c    = v < bv[s];
        const float vmin = c ? v : bv[s];
        const float vmax = c ? bv[s] : v;
        const int   imin = c ? ci : bi[s];
        const int   imax = c ? bi[s] : ci;
        bv[s] = vmin; bi[s] = imin;
        v = vmax; ci = imax;
    }
}

// ---- Kernel 1 (fat): blocks [0,512) = fp64-MFMA projection; rest = pack C ----
// (R6: fusion measured ~90us win -- pack_c HBM traffic hides under proj's f64 pipe)
__global__ __launch_bounds__(256) void proj_packc_kernel(const float* __restrict__ Q,
                                                         const float* __restrict__ W,
                                                         const float* __restrict__ bias,
                                                         const float* __restrict__ C,
                                                         double* __restrict__ P64,
                                                         unsigned short* __restrict__ Cbf,
                                                         float* __restrict__ csq)
{
    const int bid = blockIdx.x;
    if (bid >= PROJ_BLKS) {
        // ---------------- pack_c branch ----------------
        int wave = threadIdx.x >> 6;
        int lane = threadIdx.x & 63;
        int row  = (bid - PROJ_BLKS) * 4 + wave;
        const float* x = C + (size_t)row * D_DIM;
        float s = 0.f;
        #pragma unroll
        for (int i = 0; i < 4; ++i) {
            float4 v = *(const float4*)&x[lane * 4 + i * 256];
            s += v.x * v.x + v.y * v.y + v.z * v.z + v.w * v.w;
            ushort4 h;
            h.x = f2bf(v.x); h.y = f2bf(v.y); h.z = f2bf(v.z); h.w = f2bf(v.w);
            *(ushort4*)&Cbf[(size_t)row * D_DIM + lane * 4 + i * 256] = h;
        }
        #pragma unroll
        for (int off = 32; off; off >>= 1) s += __shfl_down(s, off, 64);
        if (lane == 0) csq[row] = s;
        return;
    }
    // ---------------- proj branch ----------------
    __shared__ float Qs[PBM][PBK + PPAD];
    __shared__ float Ws[PBN][PBK + PPAD];

    const int t    = threadIdx.x;
    const int lane = t & 63;
    const int w    = t >> 6;          // wave 0..3
    const int l15  = lane & 15;
    const int l4   = lane >> 4;       // 0..3
    const int m0   = (bid >> 4) * PBM;
    const int n0   = (bid & 15) * PBN;
    const int wm   = (w >> 1) * 64;   // wave row offset in tile
    const int wn   = (w & 1) * 32;    // wave col offset in tile

    const int srow = t >> 2;          // 0..63 staging row
    const int scol = (t & 3) * 4;     // staging float4 col

    f64x4 acc[4][2];
    #pragma unroll
    for (int fm = 0; fm < 4; ++fm)
        #pragma unroll
        for (int fn = 0; fn < 2; ++fn) acc[fm][fn] = (f64x4)0.0;

    for (int k0 = 0; k0 < D_DIM; k0 += PBK) {
        float4 qa0 = *(const float4*)&Q[(size_t)(m0 + srow)      * D_DIM + k0 + scol];
        float4 qa1 = *(const float4*)&Q[(size_t)(m0 + srow + 64) * D_DIM + k0 + scol];
        float4 wa  = *(const float4*)&W[(size_t)(n0 + srow)      * D_DIM + k0 + scol];
        __syncthreads();   // previous-iteration readers done
        *(float4*)&Qs[srow][scol]      = qa0;
        *(float4*)&Qs[srow + 64][scol] = qa1;
        *(float4*)&Ws[srow][scol]      = wa;
        __syncthreads();   // tile visible to all waves

        #pragma unroll
        for (int ks = 0; ks < 4; ++ks) {
            const int kc = ks * 4 + l4;
            double a[4], b[2];
            #pragma unroll
            for (int fm = 0; fm < 4; ++fm) a[fm] = (double)Qs[wm + fm * 16 + l15][kc];
            #pragma unroll
            for (int fn = 0; fn < 2; ++fn) b[fn] = (double)Ws[wn + fn * 16 + l15][kc];
            #pragma unroll
            for (int fm = 0; fm < 4; ++fm)
                #pragma unroll
                for (int fn = 0; fn < 2; ++fn)
                    acc[fm][fn] = __builtin_amdgcn_mfma_f64_16x16x4f64(a[fm], b[fn], acc[fm][fn], 0, 0, 0);
        }
    }

    #pragma unroll
    for (int fm = 0; fm < 4; ++fm) {
        #pragma unroll
        for (int fn = 0; fn < 2; ++fn) {
            const int col = n0 + wn + fn * 16 + l15;
            const double bv = (double)bias[col];
            #pragma unroll
            for (int j = 0; j < 4; ++j) {
                const int row = m0 + wm + fm * 16 + j * 4 + l4;   // f64 shape: reg strides 4 rows
                P64[(size_t)row * D_DIM + col] = acc[fm][fn][j] + bv;
            }
        }
    }
}

// ---- Kernel 1b: measure the actual within-16 row permutation of P64 ----
__global__ __launch_bounds__(256) void perm_detect_kernel(const float* __restrict__ Q,
                                                          const float* __restrict__ W,
                                                          const float* __restrict__ bias,
                                                          const double* __restrict__ P64,
                                                          int* __restrict__ invperm)
{
    __shared__ double tv[16];
    const int t = threadIdx.x;      // 256 threads
    const int g = t >> 4;           // true row 0..15
    const int s = t & 15;           // k-slice
    if (t < 16) invperm[t] = t;     // identity default (overwritten below)

    double acc = 0.0;
    const int kb = s * 64;
    for (int k = 0; k < 64; ++k)
        acc = fma((double)Q[(size_t)g * D_DIM + kb + k], (double)W[kb + k], acc);
    #pragma unroll
    for (int off = 8; off; off >>= 1) acc += __shfl_down(acc, off, 16);
    if (s == 0) tv[g] = acc + (double)bias[0];
    __syncthreads();

    if (t < 16) {
        double p = P64[(size_t)t * D_DIM];   // physical row t, col 0
        int best = 0; double bd = fabs(p - tv[0]);
        #pragma unroll
        for (int i = 1; i < 16; ++i) {
            double d = fabs(p - tv[i]);
            if (d < bd) { bd = d; best = i; }
        }
        invperm[best] = t;   // physical row t holds true row `best`
    }
}

// ---- Kernel 3: pack P64 -> bf16 Pbf + fp32 qsq (reads physical rows via invperm) ----
__global__ __launch_bounds__(256) void pack_q_kernel(const double* __restrict__ P64,
                                                     const int* __restrict__ invperm,
                                                     unsigned short* __restrict__ Pbf,
                                                     float* __restrict__ qsq)
{
    int wave = threadIdx.x >> 6;
    int lane = threadIdx.x & 63;
    int row  = blockIdx.x * 4 + wave;                 // true row
    int prow = (row & ~15) | invperm[row & 15];       // physical row in P64
    const double* x = P64 + (size_t)prow * D_DIM;
    float s = 0.f;
    #pragma unroll
    for (int j = 0; j < 8; ++j) {
        double2 v = *(const double2*)&x[lane * 2 + j * 128];
        float a = (float)v.x, b = (float)v.y;
        s += a * a + b * b;
        ushort2 h; h.x = f2bf(a); h.y = f2bf(b);
        *(ushort2*)&Pbf[(size_t)row * D_DIM + lane * 2 + j * 128] = h;
    }
    #pragma unroll
    for (int off = 32; off; off >>= 1) s += __shfl_down(s, off, 64);
    if (lane == 0) qsq[row] = s;
}

// ---- Kernel 4: bf16-MFMA screening GEMM + per-lane register top-5 ----
// R7: 512-thread blocks, 8 waves = (wq query-half, wc context-quarter).
// One staged C-tile serves 128 queries -> C re-read volume halves vs QT=64.
// Staging structure identical to R5 (global_load_lds + source XOR swizzle,
// single buffer, 2 barriers/K-step -- R6 proved reg-staging is -44%).
// grid: (CSPLIT, NQ/QT=8, B) = 256 blocks, 1/CU, 8 waves/CU.
__global__ __launch_bounds__(512, 2) void dist_mfma_kernel(const unsigned short* __restrict__ Pbf,
                                                           const unsigned short* __restrict__ Cbf,
                                                           const float* __restrict__ qsq,
                                                           const float* __restrict__ csq,
                                                           int* __restrict__ pi)
{
    __shared__ __align__(16) short CsS[CTILE * 64];  // 32 KB
    __shared__ __align__(16) short QsS[QT * 64];     // 16 KB
    float* MV = (float*)CsS;                         // merge alias: [128][4][TOPA] = 10 KB
    int*   MI = (int*)(CsS + 5120);                  // 10 KB offset

    const int t    = threadIdx.x;
    const int lane = t & 63;
    const int w    = t >> 6;       // wave 0..7
    const int wq   = w >> 2;       // query half 0..1
    const int wc   = w & 3;        // context quarter 0..3
    const int l15  = lane & 15;
    const int l4   = lane >> 4;    // 0..3
    const int r8   = lane >> 3;    // 0..7 (staging sub-row)
    const int sc   = lane & 7;     // staging store-chunk
    const int csplit = blockIdx.x;
    const int by = blockIdx.y;
    const int bz = blockIdx.z;
    const int qg0 = bz * NQ + by * QT;

    // loop-invariant lane-relative staging offsets (elements).
    // Each wave stages 32 C rows (4 gloads) + 16 Q rows (2 gloads).
    unsigned cOff[4], qOff[2];
    #pragma unroll
    for (int j = 0; j < 4; ++j)
        cOff[j] = (unsigned)((wc * 64 + wq * 32 + j * 8 + r8) * D_DIM + (sc ^ r8) * 8);
    #pragma unroll
    for (int j = 0; j < 2; ++j)
        qOff[j] = (unsigned)((w * 16 + j * 8 + r8) * D_DIM + (sc ^ r8) * 8);

    float qsv[4];
    #pragma unroll
    for (int s = 0; s < 4; ++s) qsv[s] = qsq[qg0 + wq * 64 + s * 16 + l15];

    float bv[4][TOPA]; int bi[4][TOPA];
    #pragma unroll
    for (int s = 0; s < 4; ++s)
        #pragma unroll
        for (int j = 0; j < TOPA; ++j) { bv[s][j] = FLT_MAX; bi[s][j] = 0x7fffffff; }

    const int cpb = NC / CSPLIT;   // 2048
    for (int it = 0; it < cpb / CTILE; ++it) {
        const int cg0 = csplit * cpb + it * CTILE;
        const size_t crow0 = (size_t)bz * NC + cg0;

        f32x4 acc[4][4];
        #pragma unroll
        for (int u = 0; u < 4; ++u)
            #pragma unroll
            for (int s = 0; s < 4; ++s) acc[u][s] = (f32x4)0.0f;

        for (int k0 = 0; k0 < D_DIM; k0 += BK) {
            const unsigned short* cB = Cbf + crow0 * D_DIM + k0;
            const unsigned short* qB = Pbf + (size_t)qg0 * D_DIM + k0;
            __syncthreads();   // all waves done reading previous LDS contents
            #pragma unroll
            for (int j = 0; j < 4; ++j)
                gload16(cB + cOff[j], &CsS[(wc * 64 + wq * 32 + j * 8) * 64]);
            #pragma unroll
            for (int j = 0; j < 2; ++j)
                gload16(qB + qOff[j], &QsS[(w * 16 + j * 8) * 64]);
            __syncthreads();   // vmcnt drained before barrier -> LDS filled
            #pragma unroll
            for (int ks = 0; ks < 2; ++ks) {
                const int sp = ((ks * 4 + l4) ^ (l15 & 7)) * 8;
                bf16x8 bq[4], ac[4];
                #pragma unroll
                for (int s = 0; s < 4; ++s)
                    bq[s] = *(const bf16x8*)&QsS[(wq * 64 + s * 16 + l15) * 64 + sp];
                #pragma unroll
                for (int u = 0; u < 4; ++u)
                    ac[u] = *(const bf16x8*)&CsS[(wc * 64 + u * 16 + l15) * 64 + sp];
                #pragma unroll
                for (int u = 0; u < 4; ++u)
                    #pragma unroll
                    for (int s = 0; s < 4; ++s)
                        acc[u][s] = __builtin_amdgcn_mfma_f32_16x16x32_bf16(ac[u], bq[s], acc[u][s], 0, 0, 0);
            }
        }

        // d^2 = |q|^2 + |c|^2 - 2 q.c  -> branchless per-lane register top-5
        #pragma unroll
        for (int u = 0; u < 4; ++u) {
            const int crow = wc * 64 + u * 16 + l4 * 4;
            float4 cs4 = *(const float4*)&csq[(size_t)bz * NC + cg0 + crow];
            float csa[4] = {cs4.x, cs4.y, cs4.z, cs4.w};
            #pragma unroll
            for (int s = 0; s < 4; ++s) {
                #pragma unroll
                for (int r = 0; r < 4; ++r) {
                    float v = qsv[s] + csa[r] - 2.0f * acc[u][s][r];
                    ins5b(bv[s], bi[s], v, cg0 + crow + r);
                }
            }
        }
    }

    // wave-level merge across l4 groups (same query columns) via shuffles
    #pragma unroll
    for (int mask = 16; mask <= 32; mask <<= 1) {
        #pragma unroll
        for (int s = 0; s < 4; ++s) {
            float ov[TOPA]; int oi[TOPA];
            #pragma unroll
            for (int j = 0; j < TOPA; ++j) {
                ov[j] = __shfl_xor(bv[s][j], mask, 64);
                oi[j] = __shfl_xor(bi[s][j], mask, 64);
            }
            #pragma unroll
            for (int j = 0; j < TOPA; ++j) insN<TOPA>(bv[s], bi[s], ov[j], oi[j]);
        }
    }
    // cross-wave merge via LDS: 4 wc-lists per query
    __syncthreads();
    if (l4 == 0) {
        #pragma unroll
        for (int s = 0; s < 4; ++s) {
            int q = wq * 64 + s * 16 + l15;
            #pragma unroll
            for (int j = 0; j < TOPA; ++j) {
                MV[(q * 4 + wc) * TOPA + j] = bv[s][j];
                MI[(q * 4 + wc) * TOPA + j] = bi[s][j];
            }
        }
    }
    __syncthreads();
    if (t < QT) {
        float mv[TOPA]; int mi[TOPA];
        #pragma unroll
        for (int j = 0; j < TOPA; ++j) { mv[j] = FLT_MAX; mi[j] = 0x7fffffff; }
        for (int l = 0; l < 4; ++l)
            #pragma unroll
            for (int j = 0; j < TOPA; ++j)
                insN<TOPA>(mv, mi, MV[(t * 4 + l) * TOPA + j], MI[(t * 4 + l) * TOPA + j]);
        size_t base = (((size_t)qg0 + t) * CSPLIT + csplit) * TOPA;
        #pragma unroll
        for (int j = 0; j < TOPA; ++j) pi[base + j] = mi[j];
    }
}

// ---- Kernel 5: fp64 exact refine of 40 candidates per query -> top-5, sqrt, outputs ----
__global__ __launch_bounds__(256) void refine_kernel(const double* __restrict__ P64,
                                                     const int* __restrict__ invperm,
                                                     const float* __restrict__ C,
                                                     const int*   __restrict__ pi,
                                                     float* __restrict__ out)
{
    __shared__ double dvs[CAND];
    __shared__ int    dis[CAND];
    const int q    = blockIdx.x;                      // true row
    const int pq   = (q & ~15) | invperm[q & 15];     // physical row in P64
    const int bz   = q >> 10;
    const int t    = threadIdx.x;
    const int wave = t >> 6;
    const int lane = t & 63;
    const double* p = P64 + (size_t)pq * D_DIM;

    for (int k = wave; k < CAND; k += 4) {
        int ci = pi[(size_t)q * CAND + k];
        const float* c = C + ((size_t)bz * NC + ci) * D_DIM;
        double s = 0.0;
        #pragma unroll
        for (int j = 0; j < 16; ++j) {
            int d = lane + 64 * j;
            double diff = p[d] - (double)c[d];
            s = fma(diff, diff, s);
        }
        #pragma unroll
        for (int off = 32; off; off >>= 1) s += __shfl_down(s, off, 64);
        if (lane == 0) { dvs[k] = s; dis[k] = ci; }
    }
    __syncthreads();
    if (t == 0) {
        double bv[TOPN]; int bi[TOPN];
        #pragma unroll
        for (int j = 0; j < TOPN; ++j) { bv[j] = DBL_MAX; bi[j] = 0x7fffffff; }
        for (int k = 0; k < CAND; ++k)
            topk_insert<TOPN,double>(bv, bi, dvs[k], dis[k]);
        #pragma unroll
        for (int j = 0; j < TOPN; ++j) {
            out[(size_t)q * TOPN + j] = (float)sqrt(bv[j]);
            out[(size_t)B_DIM * NQ * TOPN + (size_t)q * TOPN + j] = (float)bi[j];
        }
    }
}

extern "C" void kernel_launch(void* const* d_in, const int* in_sizes, int n_in,
                              void* d_out, int out_size, void* d_ws, size_t ws_size,
                              hipStream_t stream) {
    const float* Q    = (const float*)d_in[0];
    const float* C    = (const float*)d_in[1];
    const float* W    = (const float*)d_in[2];
    const float* bias = (const float*)d_in[3];
    float* out = (float*)d_out;

    char* ws = (char*)d_ws;
    double*         P64 = (double*)ws;                                       // 32 MB
    unsigned short* Pbf = (unsigned short*)(ws + (size_t)32 * 1024 * 1024);  //  8 MB
    unsigned short* Cbf = (unsigned short*)(ws + (size_t)40 * 1024 * 1024);  // 128 MB
    float*          qsq = (float*)(ws + (size_t)168 * 1024 * 1024);          // 16 KB
    float*          csq = qsq + 4096;                                        // 256 KB
    int*            pi  = (int*)(csq + 65536);                               // 655 KB
    int*            ivp = pi + (size_t)B_DIM * NQ * CAND;                    // 64 B
    // total ~170 MB of workspace

    proj_packc_kernel<<<PROJ_BLKS + (B_DIM * NC) / 4, 256, 0, stream>>>(Q, W, bias, C, P64, Cbf, csq);
    perm_detect_kernel<<<1, 256, 0, stream>>>(Q, W, bias, P64, ivp);
    pack_q_kernel<<<(B_DIM * NQ) / 4, 256, 0, stream>>>(P64, ivp, Pbf, qsq);
    dist_mfma_kernel<<<dim3(CSPLIT, NQ / QT, B_DIM), 512, 0, stream>>>(Pbf, Cbf, qsq, csq, pi);
    refine_kernel<<<B_DIM * NQ, 256, 0, stream>>>(P64, ivp, C, pi, out);
}

// Round 8
// 862.190 us; speedup vs baseline: 1.0896x; 1.0623x over previous
//
#include <hip/hip_runtime.h>
#include <cfloat>
#include <math.h>

#define D_DIM 1024
#define B_DIM 4
#define NQ    1024
#define NC    16384
#define TOPN  5
#define TOPA  5               // stage-A candidates per context split
#define CSPLIT 8              // context splits per batch
#define CAND  (TOPA*CSPLIT)   // 40 candidates per query
#define QT    64              // queries per block (dist kernel; R7's 128 was -25%)
#define CTILE 256             // contexts per tile iteration (dist kernel)
#define BK    64              // K per LDS stage (bf16 elements)

// proj (fp64 MFMA) tiling
#define PBM 128
#define PBN 64
#define PBK 32   // R8: 16->32 halves barrier count (proj floor ~109us vs ~128 full-drain barriers)
#define PPAD 4   // row stride 36 floats = 144 B = 9x16 -> float4 LDS stores stay 16B-aligned
#define PROJ_BLKS ((D_DIM/PBN) * ((B_DIM*NQ)/PBM))   // 512

typedef __bf16 bf16x8 __attribute__((ext_vector_type(8)));
typedef float  f32x4  __attribute__((ext_vector_type(4)));
typedef double f64x4  __attribute__((ext_vector_type(4)));

__device__ __forceinline__ unsigned short f2bf(float f) {
    unsigned u = __builtin_bit_cast(unsigned, f);
    unsigned r = (u + 0x7fffu + ((u >> 16) & 1u)) >> 16;
    return (unsigned short)r;
}

// async global->LDS, 16B per lane; LDS dest = wave-uniform base + lane*16
__device__ __forceinline__ void gload16(const void* g, void* l) {
    __builtin_amdgcn_global_load_lds(
        (const __attribute__((address_space(1))) unsigned*)g,
        (__attribute__((address_space(3))) unsigned*)l, 16, 0, 0);
}

// ---- lexicographic (value, index) top-N insert (used by fp64 refine) ----
template<int N, typename T>
__device__ __forceinline__ void topk_insert(T (&bv)[N], int (&bi)[N], T v, int ci) {
    if (v < bv[N-1] || (v == bv[N-1] && ci < bi[N-1])) {
        bv[N-1] = v; bi[N-1] = ci;
        #pragma unroll
        for (int s = N-1; s > 0; --s) {
            bool sw = (bv[s] < bv[s-1]) || (bv[s] == bv[s-1] && bi[s] < bi[s-1]);
            if (sw) {
                T tv = bv[s-1]; bv[s-1] = bv[s]; bv[s] = tv;
                int ti = bi[s-1]; bi[s-1] = bi[s]; bi[s] = ti;
            }
        }
    }
}

// ---- value-only top-N insert (merge phases; ties resolved by fp64 refine) ----
template<int N>
__device__ __forceinline__ void insN(float (&bv)[N], int (&bi)[N], float v, int ci) {
    if (v < bv[N-1]) {
        bv[N-1] = v; bi[N-1] = ci;
        #pragma unroll
        for (int s = N-1; s > 0; --s) {
            if (bv[s] < bv[s-1]) {
                float tv = bv[s-1]; bv[s-1] = bv[s]; bv[s] = tv;
                int   ti = bi[s-1]; bi[s-1] = bi[s]; bi[s] = ti;
            }
        }
    }
}

// ---- branchless sorted (value,index) top-5 insert for the hot acc drain ----
__device__ __forceinline__ void ins5b(float (&bv)[TOPA], int (&bi)[TOPA], float v, int ci) {
    #pragma unroll
    for (int s = 0; s < TOPA; ++s) {
        const bool  c    = v < bv[s];
        const float vmin = c ? v : bv[s];
        const float vmax = c ? bv[s] : v;
        const int   imin = c ? ci : bi[s];
        const int   imax = c ? bi[s] : ci;
        bv[s] = vmin; bi[s] = imin;
        v = vmax; ci = imax;
    }
}

// ---- Kernel 1 (fat): blocks [0,512) = fp64-MFMA projection; rest = pack C ----
// (fusion measured ~70-90us win: pack_c HBM traffic hides under proj's f64 pipe)
// proj: 128x64 tile, 4 waves 2x2, wave 64x32 (4x2 frags of 16x16), PBK=32.
// v_mfma_f64_16x16x4_f64: A row=l&15,k=l>>4; B col=l&15,k=l>>4; D row=4*reg+(l>>4).
__global__ __launch_bounds__(256) void proj_packc_kernel(const float* __restrict__ Q,
                                                         const float* __restrict__ W,
                                                         const float* __restrict__ bias,
                                                         const float* __restrict__ C,
                                                         double* __restrict__ P64,
                                                         unsigned short* __restrict__ Cbf,
                                                         float* __restrict__ csq)
{
    const int bid = blockIdx.x;
    if (bid >= PROJ_BLKS) {
        // ---------------- pack_c branch ----------------
        int wave = threadIdx.x >> 6;
        int lane = threadIdx.x & 63;
        int row  = (bid - PROJ_BLKS) * 4 + wave;
        const float* x = C + (size_t)row * D_DIM;
        float s = 0.f;
        #pragma unroll
        for (int i = 0; i < 4; ++i) {
            float4 v = *(const float4*)&x[lane * 4 + i * 256];
            s += v.x * v.x + v.y * v.y + v.z * v.z + v.w * v.w;
            ushort4 h;
            h.x = f2bf(v.x); h.y = f2bf(v.y); h.z = f2bf(v.z); h.w = f2bf(v.w);
            *(ushort4*)&Cbf[(size_t)row * D_DIM + lane * 4 + i * 256] = h;
        }
        #pragma unroll
        for (int off = 32; off; off >>= 1) s += __shfl_down(s, off, 64);
        if (lane == 0) csq[row] = s;
        return;
    }
    // ---------------- proj branch ----------------
    __shared__ __align__(16) float Qs[PBM][PBK + PPAD];   // 18 KB
    __shared__ __align__(16) float Ws[PBN][PBK + PPAD];   //  9 KB

    const int t    = threadIdx.x;
    const int lane = t & 63;
    const int w    = t >> 6;          // wave 0..3
    const int l15  = lane & 15;
    const int l4   = lane >> 4;       // 0..3
    const int m0   = (bid >> 4) * PBM;
    const int n0   = (bid & 15) * PBN;
    const int wm   = (w >> 1) * 64;   // wave row offset in tile
    const int wn   = (w & 1) * 32;    // wave col offset in tile

    const int srow = t >> 3;          // 0..31 staging row
    const int scol = (t & 7) * 4;     // staging float4 col (0..28)

    f64x4 acc[4][2];
    #pragma unroll
    for (int fm = 0; fm < 4; ++fm)
        #pragma unroll
        for (int fn = 0; fn < 2; ++fn) acc[fm][fn] = (f64x4)0.0;

    for (int k0 = 0; k0 < D_DIM; k0 += PBK) {
        float4 qa0 = *(const float4*)&Q[(size_t)(m0 + srow)      * D_DIM + k0 + scol];
        float4 qa1 = *(const float4*)&Q[(size_t)(m0 + srow + 32) * D_DIM + k0 + scol];
        float4 qa2 = *(const float4*)&Q[(size_t)(m0 + srow + 64) * D_DIM + k0 + scol];
        float4 qa3 = *(const float4*)&Q[(size_t)(m0 + srow + 96) * D_DIM + k0 + scol];
        float4 wa0 = *(const float4*)&W[(size_t)(n0 + srow)      * D_DIM + k0 + scol];
        float4 wa1 = *(const float4*)&W[(size_t)(n0 + srow + 32) * D_DIM + k0 + scol];
        __syncthreads();   // previous-iteration readers done
        *(float4*)&Qs[srow][scol]      = qa0;
        *(float4*)&Qs[srow + 32][scol] = qa1;
        *(float4*)&Qs[srow + 64][scol] = qa2;
        *(float4*)&Qs[srow + 96][scol] = qa3;
        *(float4*)&Ws[srow][scol]      = wa0;
        *(float4*)&Ws[srow + 32][scol] = wa1;
        __syncthreads();   // tile visible to all waves

        #pragma unroll
        for (int ks = 0; ks < PBK / 4; ++ks) {
            const int kc = ks * 4 + l4;
            double a[4], b[2];
            #pragma unroll
            for (int fm = 0; fm < 4; ++fm) a[fm] = (double)Qs[wm + fm * 16 + l15][kc];
            #pragma unroll
            for (int fn = 0; fn < 2; ++fn) b[fn] = (double)Ws[wn + fn * 16 + l15][kc];
            #pragma unroll
            for (int fm = 0; fm < 4; ++fm)
                #pragma unroll
                for (int fn = 0; fn < 2; ++fn)
                    acc[fm][fn] = __builtin_amdgcn_mfma_f64_16x16x4f64(a[fm], b[fn], acc[fm][fn], 0, 0, 0);
        }
    }

    #pragma unroll
    for (int fm = 0; fm < 4; ++fm) {
        #pragma unroll
        for (int fn = 0; fn < 2; ++fn) {
            const int col = n0 + wn + fn * 16 + l15;
            const double bv = (double)bias[col];
            #pragma unroll
            for (int j = 0; j < 4; ++j) {
                const int row = m0 + wm + fm * 16 + j * 4 + l4;   // f64 shape: reg strides 4 rows
                P64[(size_t)row * D_DIM + col] = acc[fm][fn][j] + bv;
            }
        }
    }
}

// ---- Kernel 1b: measure the actual within-16 row permutation of P64 ----
__global__ __launch_bounds__(256) void perm_detect_kernel(const float* __restrict__ Q,
                                                          const float* __restrict__ W,
                                                          const float* __restrict__ bias,
                                                          const double* __restrict__ P64,
                                                          int* __restrict__ invperm)
{
    __shared__ double tv[16];
    const int t = threadIdx.x;      // 256 threads
    const int g = t >> 4;           // true row 0..15
    const int s = t & 15;           // k-slice
    if (t < 16) invperm[t] = t;     // identity default (overwritten below)

    double acc = 0.0;
    const int kb = s * 64;
    for (int k = 0; k < 64; ++k)
        acc = fma((double)Q[(size_t)g * D_DIM + kb + k], (double)W[kb + k], acc);
    #pragma unroll
    for (int off = 8; off; off >>= 1) acc += __shfl_down(acc, off, 16);
    if (s == 0) tv[g] = acc + (double)bias[0];
    __syncthreads();

    if (t < 16) {
        double p = P64[(size_t)t * D_DIM];   // physical row t, col 0
        int best = 0; double bd = fabs(p - tv[0]);
        #pragma unroll
        for (int i = 1; i < 16; ++i) {
            double d = fabs(p - tv[i]);
            if (d < bd) { bd = d; best = i; }
        }
        invperm[best] = t;   // physical row t holds true row `best`
    }
}

// ---- Kernel 3: pack P64 -> bf16 Pbf + fp32 qsq (reads physical rows via invperm) ----
__global__ __launch_bounds__(256) void pack_q_kernel(const double* __restrict__ P64,
                                                     const int* __restrict__ invperm,
                                                     unsigned short* __restrict__ Pbf,
                                                     float* __restrict__ qsq)
{
    int wave = threadIdx.x >> 6;
    int lane = threadIdx.x & 63;
    int row  = blockIdx.x * 4 + wave;                 // true row
    int prow = (row & ~15) | invperm[row & 15];       // physical row in P64
    const double* x = P64 + (size_t)prow * D_DIM;
    float s = 0.f;
    #pragma unroll
    for (int j = 0; j < 8; ++j) {
        double2 v = *(const double2*)&x[lane * 2 + j * 128];
        float a = (float)v.x, b = (float)v.y;
        s += a * a + b * b;
        ushort2 h; h.x = f2bf(a); h.y = f2bf(b);
        *(ushort2*)&Pbf[(size_t)row * D_DIM + lane * 2 + j * 128] = h;
    }
    #pragma unroll
    for (int off = 32; off; off >>= 1) s += __shfl_down(s, off, 64);
    if (lane == 0) qsq[row] = s;
}

// ---- Kernel 4: bf16-MFMA screening GEMM + per-lane register top-5 ----
// EXACT R5 structure (measured 240us): 256 threads / 4 waves, QT=64, CTILE=256,
// single-buffer global_load_lds staging with source XOR swizzle, 2 barriers/K-step.
// (Falsified alternatives: reg-staged C -44% (R6), QT=128 8-wave -25% (R7),
//  LDS double-buffer -5% (R4).)
__global__ __launch_bounds__(256, 3) void dist_mfma_kernel(const unsigned short* __restrict__ Pbf,
                                                           const unsigned short* __restrict__ Cbf,
                                                           const float* __restrict__ qsq,
                                                           const float* __restrict__ csq,
                                                           int* __restrict__ pi)
{
    __shared__ __align__(16) short CsS[CTILE * 64];  // 32 KB
    __shared__ __align__(16) short QsS[QT * 64];     //  8 KB
    float* MV = (float*)CsS;                         // merge alias: [64][4][TOPA]
    int*   MI = (int*)(CsS + 4096);                  // 8 KB offset

    const int t    = threadIdx.x;
    const int lane = t & 63;
    const int w    = t >> 6;       // wave 0..3 -> context quarter
    const int l15  = lane & 15;
    const int l4   = lane >> 4;    // 0..3
    const int r8   = lane >> 3;    // 0..7 (staging sub-row)
    const int sc   = lane & 7;     // staging store-chunk
    const int csplit = blockIdx.x;
    const int by = blockIdx.y;
    const int bz = blockIdx.z;
    const int qg0 = bz * NQ + by * QT;

    // loop-invariant lane-relative staging offsets (elements)
    unsigned cOff[8], qOff[2];
    #pragma unroll
    for (int j = 0; j < 8; ++j)
        cOff[j] = (unsigned)((w * 64 + j * 8 + r8) * D_DIM + (sc ^ r8) * 8);
    #pragma unroll
    for (int j = 0; j < 2; ++j)
        qOff[j] = (unsigned)((w * 16 + j * 8 + r8) * D_DIM + (sc ^ r8) * 8);

    float qsv[4];
    #pragma unroll
    for (int s = 0; s < 4; ++s) qsv[s] = qsq[qg0 + s * 16 + l15];

    float bv[4][TOPA]; int bi[4][TOPA];
    #pragma unroll
    for (int s = 0; s < 4; ++s)
        #pragma unroll
        for (int j = 0; j < TOPA; ++j) { bv[s][j] = FLT_MAX; bi[s][j] = 0x7fffffff; }

    const int cpb = NC / CSPLIT;   // 2048
    for (int it = 0; it < cpb / CTILE; ++it) {
        const int cg0 = csplit * cpb + it * CTILE;
        const size_t crow0 = (size_t)bz * NC + cg0;

        f32x4 acc[4][4];
        #pragma unroll
        for (int u = 0; u < 4; ++u)
            #pragma unroll
            for (int s = 0; s < 4; ++s) acc[u][s] = (f32x4)0.0f;

        for (int k0 = 0; k0 < D_DIM; k0 += BK) {
            const unsigned short* cB = Cbf + crow0 * D_DIM + k0;
            const unsigned short* qB = Pbf + (size_t)qg0 * D_DIM + k0;
            __syncthreads();   // all waves done reading previous LDS contents
            #pragma unroll
            for (int j = 0; j < 8; ++j)
                gload16(cB + cOff[j], &CsS[(w * 64 + j * 8) * 64]);
            #pragma unroll
            for (int j = 0; j < 2; ++j)
                gload16(qB + qOff[j], &QsS[(w * 16 + j * 8) * 64]);
            __syncthreads();   // vmcnt drained before barrier -> LDS filled
            #pragma unroll
            for (int ks = 0; ks < 2; ++ks) {
                const int sp = ((ks * 4 + l4) ^ (l15 & 7)) * 8;
                bf16x8 bq[4], ac[4];
                #pragma unroll
                for (int s = 0; s < 4; ++s)
                    bq[s] = *(const bf16x8*)&QsS[(s * 16 + l15) * 64 + sp];
                #pragma unroll
                for (int u = 0; u < 4; ++u)
                    ac[u] = *(const bf16x8*)&CsS[(w * 64 + u * 16 + l15) * 64 + sp];
                #pragma unroll
                for (int u = 0; u < 4; ++u)
                    #pragma unroll
                    for (int s = 0; s < 4; ++s)
                        acc[u][s] = __builtin_amdgcn_mfma_f32_16x16x32_bf16(ac[u], bq[s], acc[u][s], 0, 0, 0);
            }
        }

        // d^2 = |q|^2 + |c|^2 - 2 q.c  -> branchless per-lane register top-5
        #pragma unroll
        for (int u = 0; u < 4; ++u) {
            const int crow = w * 64 + u * 16 + l4 * 4;
            float4 cs4 = *(const float4*)&csq[(size_t)bz * NC + cg0 + crow];
            float csa[4] = {cs4.x, cs4.y, cs4.z, cs4.w};
            #pragma unroll
            for (int s = 0; s < 4; ++s) {
                #pragma unroll
                for (int r = 0; r < 4; ++r) {
                    float v = qsv[s] + csa[r] - 2.0f * acc[u][s][r];
                    ins5b(bv[s], bi[s], v, cg0 + crow + r);
                }
            }
        }
    }

    // wave-level merge across l4 groups (same query columns) via shuffles
    #pragma unroll
    for (int mask = 16; mask <= 32; mask <<= 1) {
        #pragma unroll
        for (int s = 0; s < 4; ++s) {
            float ov[TOPA]; int oi[TOPA];
            #pragma unroll
            for (int j = 0; j < TOPA; ++j) {
                ov[j] = __shfl_xor(bv[s][j], mask, 64);
                oi[j] = __shfl_xor(bi[s][j], mask, 64);
            }
            #pragma unroll
            for (int j = 0; j < TOPA; ++j) insN<TOPA>(bv[s], bi[s], ov[j], oi[j]);
        }
    }
    // cross-wave merge via LDS (l4==0 lanes hold wave-merged lists)
    __syncthreads();
    if (l4 == 0) {
        #pragma unroll
        for (int s = 0; s < 4; ++s) {
            int q = s * 16 + l15;
            #pragma unroll
            for (int j = 0; j < TOPA; ++j) {
                MV[(q * 4 + w) * TOPA + j] = bv[s][j];
                MI[(q * 4 + w) * TOPA + j] = bi[s][j];
            }
        }
    }
    __syncthreads();
    if (t < QT) {
        float mv[TOPA]; int mi[TOPA];
        #pragma unroll
        for (int j = 0; j < TOPA; ++j) { mv[j] = FLT_MAX; mi[j] = 0x7fffffff; }
        for (int l = 0; l < 4; ++l)
            #pragma unroll
            for (int j = 0; j < TOPA; ++j)
                insN<TOPA>(mv, mi, MV[(t * 4 + l) * TOPA + j], MI[(t * 4 + l) * TOPA + j]);
        size_t base = (((size_t)qg0 + t) * CSPLIT + csplit) * TOPA;
        #pragma unroll
        for (int j = 0; j < TOPA; ++j) pi[base + j] = mi[j];
    }
}

// ---- Kernel 5: fp64 exact refine of 40 candidates per query -> top-5, sqrt, outputs ----
__global__ __launch_bounds__(256) void refine_kernel(const double* __restrict__ P64,
                                                     const int* __restrict__ invperm,
                                                     const float* __restrict__ C,
                                                     const int*   __restrict__ pi,
                                                     float* __restrict__ out)
{
    __shared__ double dvs[CAND];
    __shared__ int    dis[CAND];
    const int q    = blockIdx.x;                      // true row
    const int pq   = (q & ~15) | invperm[q & 15];     // physical row in P64
    const int bz   = q >> 10;
    const int t    = threadIdx.x;
    const int wave = t >> 6;
    const int lane = t & 63;
    const double* p = P64 + (size_t)pq * D_DIM;

    for (int k = wave; k < CAND; k += 4) {
        int ci = pi[(size_t)q * CAND + k];
        const float* c = C + ((size_t)bz * NC + ci) * D_DIM;
        double s = 0.0;
        #pragma unroll
        for (int j = 0; j < 16; ++j) {
            int d = lane + 64 * j;
            double diff = p[d] - (double)c[d];
            s = fma(diff, diff, s);
        }
        #pragma unroll
        for (int off = 32; off; off >>= 1) s += __shfl_down(s, off, 64);
        if (lane == 0) { dvs[k] = s; dis[k] = ci; }
    }
    __syncthreads();
    if (t == 0) {
        double bv[TOPN]; int bi[TOPN];
        #pragma unroll
        for (int j = 0; j < TOPN; ++j) { bv[j] = DBL_MAX; bi[j] = 0x7fffffff; }
        for (int k = 0; k < CAND; ++k)
            topk_insert<TOPN,double>(bv, bi, dvs[k], dis[k]);
        #pragma unroll
        for (int j = 0; j < TOPN; ++j) {
            out[(size_t)q * TOPN + j] = (float)sqrt(bv[j]);
            out[(size_t)B_DIM * NQ * TOPN + (size_t)q * TOPN + j] = (float)bi[j];
        }
    }
}

extern "C" void kernel_launch(void* const* d_in, const int* in_sizes, int n_in,
                              void* d_out, int out_size, void* d_ws, size_t ws_size,
                              hipStream_t stream) {
    const float* Q    = (const float*)d_in[0];
    const float* C    = (const float*)d_in[1];
    const float* W    = (const float*)d_in[2];
    const float* bias = (const float*)d_in[3];
    float* out = (float*)d_out;

    char* ws = (char*)d_ws;
    double*         P64 = (double*)ws;                                       // 32 MB
    unsigned short* Pbf = (unsigned short*)(ws + (size_t)32 * 1024 * 1024);  //  8 MB
    unsigned short* Cbf = (unsigned short*)(ws + (size_t)40 * 1024 * 1024);  // 128 MB
    float*          qsq = (float*)(ws + (size_t)168 * 1024 * 1024);          // 16 KB
    float*          csq = qsq + 4096;                                        // 256 KB
    int*            pi  = (int*)(csq + 65536);                               // 655 KB
    int*            ivp = pi + (size_t)B_DIM * NQ * CAND;                    // 64 B
    // total ~170 MB of workspace

    proj_packc_kernel<<<PROJ_BLKS + (B_DIM * NC) / 4, 256, 0, stream>>>(Q, W, bias, C, P64, Cbf, csq);
    perm_detect_kernel<<<1, 256, 0, stream>>>(Q, W, bias, P64, ivp);
    pack_q_kernel<<<(B_DIM * NQ) / 4, 256, 0, stream>>>(P64, ivp, Pbf, qsq);
    dist_mfma_kernel<<<dim3(CSPLIT, NQ / QT, B_DIM), 256, 0, stream>>>(Pbf, Cbf, qsq, csq, pi);
    refine_kernel<<<B_DIM * NQ, 256, 0, stream>>>(P64, ivp, C, pi, out);
}

// Round 9
// 857.580 us; speedup vs baseline: 1.0955x; 1.0054x over previous
//
#include <hip/hip_runtime.h>
#include <cfloat>
#include <math.h>

#define D_DIM 1024
#define B_DIM 4
#define NQ    1024
#define NC    16384
#define TOPN  5
#define TOPA  5               // stage-A candidates per context split
#define CSPLIT 8              // context splits per batch
#define CAND  (TOPA*CSPLIT)   // 40 candidates per query
#define QT    64              // queries per block (dist kernel; R7's 128 was -25%)
#define CTILE 256             // contexts per tile iteration (dist kernel)
#define BK    64              // K per LDS stage (bf16 elements)

// proj (fp64 MFMA) tiling
#define PBM 128
#define PBN 64
#define PBK 32
#define PPAD 4   // row stride 36 floats = 144 B = 9x16 -> float4 LDS stores stay 16B-aligned
#define PROJ_BLKS ((D_DIM/PBN) * ((B_DIM*NQ)/PBM))   // 512

typedef __bf16 bf16x8 __attribute__((ext_vector_type(8)));
typedef float  f32x4  __attribute__((ext_vector_type(4)));
typedef double f64x4  __attribute__((ext_vector_type(4)));

__device__ __forceinline__ unsigned short f2bf(float f) {
    unsigned u = __builtin_bit_cast(unsigned, f);
    unsigned r = (u + 0x7fffu + ((u >> 16) & 1u)) >> 16;
    return (unsigned short)r;
}

// async global->LDS, 16B per lane; LDS dest = wave-uniform base + lane*16
__device__ __forceinline__ void gload16(const void* g, void* l) {
    __builtin_amdgcn_global_load_lds(
        (const __attribute__((address_space(1))) unsigned*)g,
        (__attribute__((address_space(3))) unsigned*)l, 16, 0, 0);
}

// ---- lexicographic (value, index) top-N insert (used by fp64 refine) ----
template<int N, typename T>
__device__ __forceinline__ void topk_insert(T (&bv)[N], int (&bi)[N], T v, int ci) {
    if (v < bv[N-1] || (v == bv[N-1] && ci < bi[N-1])) {
        bv[N-1] = v; bi[N-1] = ci;
        #pragma unroll
        for (int s = N-1; s > 0; --s) {
            bool sw = (bv[s] < bv[s-1]) || (bv[s] == bv[s-1] && bi[s] < bi[s-1]);
            if (sw) {
                T tv = bv[s-1]; bv[s-1] = bv[s]; bv[s] = tv;
                int ti = bi[s-1]; bi[s-1] = bi[s]; bi[s] = ti;
            }
        }
    }
}

// ---- value-only top-N insert (merge phases; ties resolved by fp64 refine) ----
template<int N>
__device__ __forceinline__ void insN(float (&bv)[N], int (&bi)[N], float v, int ci) {
    if (v < bv[N-1]) {
        bv[N-1] = v; bi[N-1] = ci;
        #pragma unroll
        for (int s = N-1; s > 0; --s) {
            if (bv[s] < bv[s-1]) {
                float tv = bv[s-1]; bv[s-1] = bv[s]; bv[s] = tv;
                int   ti = bi[s-1]; bi[s-1] = bi[s]; bi[s] = ti;
            }
        }
    }
}

// ---- branchless sorted (value,index) top-5 insert for the hot acc drain ----
__device__ __forceinline__ void ins5b(float (&bv)[TOPA], int (&bi)[TOPA], float v, int ci) {
    #pragma unroll
    for (int s = 0; s < TOPA; ++s) {
        const bool  c    = v < bv[s];
        const float vmin = c ? v : bv[s];
        const float vmax = c ? bv[s] : v;
        const int   imin = c ? ci : bi[s];
        const int   imax = c ? bi[s] : ci;
        bv[s] = vmin; bi[s] = imin;
        v = vmax; ci = imax;
    }
}

// ---- Kernel 1 (fat): blocks [0,512) = fp64-MFMA projection (+ fused pack_q
// epilogue: writes P64, bf16 Pbf, atomically accumulates fp32 qsq); rest = pack C.
// Pbf/qsq/pi are PHYSICAL-row ordered (whatever row perm the f64 MFMA produces);
// refine reads pi[pq] / P64[pq] via invperm -- correct for ANY within-16 perm.
__global__ __launch_bounds__(256) void proj_packc_kernel(const float* __restrict__ Q,
                                                         const float* __restrict__ W,
                                                         const float* __restrict__ bias,
                                                         const float* __restrict__ C,
                                                         double* __restrict__ P64,
                                                         unsigned short* __restrict__ Pbf,
                                                         float* __restrict__ qsq,
                                                         unsigned short* __restrict__ Cbf,
                                                         float* __restrict__ csq)
{
    const int bid = blockIdx.x;
    if (bid >= PROJ_BLKS) {
        // ---------------- pack_c branch ----------------
        int wave = threadIdx.x >> 6;
        int lane = threadIdx.x & 63;
        int row  = (bid - PROJ_BLKS) * 4 + wave;
        const float* x = C + (size_t)row * D_DIM;
        float s = 0.f;
        #pragma unroll
        for (int i = 0; i < 4; ++i) {
            float4 v = *(const float4*)&x[lane * 4 + i * 256];
            s += v.x * v.x + v.y * v.y + v.z * v.z + v.w * v.w;
            ushort4 h;
            h.x = f2bf(v.x); h.y = f2bf(v.y); h.z = f2bf(v.z); h.w = f2bf(v.w);
            *(ushort4*)&Cbf[(size_t)row * D_DIM + lane * 4 + i * 256] = h;
        }
        #pragma unroll
        for (int off = 32; off; off >>= 1) s += __shfl_down(s, off, 64);
        if (lane == 0) csq[row] = s;
        return;
    }
    // ---------------- proj branch ----------------
    __shared__ __align__(16) float Qs[PBM][PBK + PPAD];   // 18 KB
    __shared__ __align__(16) float Ws[PBN][PBK + PPAD];   //  9 KB

    const int t    = threadIdx.x;
    const int lane = t & 63;
    const int w    = t >> 6;          // wave 0..3
    const int l15  = lane & 15;
    const int l4   = lane >> 4;       // 0..3
    const int m0   = (bid >> 4) * PBM;
    const int n0   = (bid & 15) * PBN;
    const int wm   = (w >> 1) * 64;   // wave row offset in tile
    const int wn   = (w & 1) * 32;    // wave col offset in tile

    const int srow = t >> 3;          // 0..31 staging row
    const int scol = (t & 7) * 4;     // staging float4 col (0..28)

    f64x4 acc[4][2];
    #pragma unroll
    for (int fm = 0; fm < 4; ++fm)
        #pragma unroll
        for (int fn = 0; fn < 2; ++fn) acc[fm][fn] = (f64x4)0.0;

    for (int k0 = 0; k0 < D_DIM; k0 += PBK) {
        float4 qa0 = *(const float4*)&Q[(size_t)(m0 + srow)      * D_DIM + k0 + scol];
        float4 qa1 = *(const float4*)&Q[(size_t)(m0 + srow + 32) * D_DIM + k0 + scol];
        float4 qa2 = *(const float4*)&Q[(size_t)(m0 + srow + 64) * D_DIM + k0 + scol];
        float4 qa3 = *(const float4*)&Q[(size_t)(m0 + srow + 96) * D_DIM + k0 + scol];
        float4 wa0 = *(const float4*)&W[(size_t)(n0 + srow)      * D_DIM + k0 + scol];
        float4 wa1 = *(const float4*)&W[(size_t)(n0 + srow + 32) * D_DIM + k0 + scol];
        __syncthreads();   // previous-iteration readers done
        *(float4*)&Qs[srow][scol]      = qa0;
        *(float4*)&Qs[srow + 32][scol] = qa1;
        *(float4*)&Qs[srow + 64][scol] = qa2;
        *(float4*)&Qs[srow + 96][scol] = qa3;
        *(float4*)&Ws[srow][scol]      = wa0;
        *(float4*)&Ws[srow + 32][scol] = wa1;
        __syncthreads();   // tile visible to all waves

        #pragma unroll
        for (int ks = 0; ks < PBK / 4; ++ks) {
            const int kc = ks * 4 + l4;
            double a[4], b[2];
            #pragma unroll
            for (int fm = 0; fm < 4; ++fm) a[fm] = (double)Qs[wm + fm * 16 + l15][kc];
            #pragma unroll
            for (int fn = 0; fn < 2; ++fn) b[fn] = (double)Ws[wn + fn * 16 + l15][kc];
            #pragma unroll
            for (int fm = 0; fm < 4; ++fm)
                #pragma unroll
                for (int fn = 0; fn < 2; ++fn)
                    acc[fm][fn] = __builtin_amdgcn_mfma_f64_16x16x4f64(a[fm], b[fn], acc[fm][fn], 0, 0, 0);
        }
    }

    // fused epilogue: P64 + bf16 Pbf + fp32 qsq (16-lane reduce + atomicAdd)
    #pragma unroll
    for (int fm = 0; fm < 4; ++fm) {
        #pragma unroll
        for (int j = 0; j < 4; ++j) {
            const int row = m0 + wm + fm * 16 + j * 4 + l4;   // physical row
            float part = 0.f;
            #pragma unroll
            for (int fn = 0; fn < 2; ++fn) {
                const int col = n0 + wn + fn * 16 + l15;
                double d = acc[fm][fn][j] + (double)bias[col];
                P64[(size_t)row * D_DIM + col] = d;
                float a = (float)d;
                part += a * a;
                Pbf[(size_t)row * D_DIM + col] = f2bf(a);
            }
            #pragma unroll
            for (int m = 1; m < 16; m <<= 1) part += __shfl_xor(part, m, 64);
            if (l15 == 0) atomicAdd(&qsq[row], part);
        }
    }
}

// ---- Kernel 1b: measure the actual within-16 row permutation of P64 ----
__global__ __launch_bounds__(256) void perm_detect_kernel(const float* __restrict__ Q,
                                                          const float* __restrict__ W,
                                                          const float* __restrict__ bias,
                                                          const double* __restrict__ P64,
                                                          int* __restrict__ invperm)
{
    __shared__ double tv[16];
    const int t = threadIdx.x;      // 256 threads
    const int g = t >> 4;           // true row 0..15
    const int s = t & 15;           // k-slice
    if (t < 16) invperm[t] = t;     // identity default (overwritten below)

    double acc = 0.0;
    const int kb = s * 64;
    for (int k = 0; k < 64; ++k)
        acc = fma((double)Q[(size_t)g * D_DIM + kb + k], (double)W[kb + k], acc);
    #pragma unroll
    for (int off = 8; off; off >>= 1) acc += __shfl_down(acc, off, 16);
    if (s == 0) tv[g] = acc + (double)bias[0];
    __syncthreads();

    if (t < 16) {
        double p = P64[(size_t)t * D_DIM];   // physical row t, col 0
        int best = 0; double bd = fabs(p - tv[0]);
        #pragma unroll
        for (int i = 1; i < 16; ++i) {
            double d = fabs(p - tv[i]);
            if (d < bd) { bd = d; best = i; }
        }
        invperm[best] = t;   // physical row t holds true row `best`
    }
}

// ---- Kernel 4: bf16-MFMA screening GEMM + per-lane register top-5 ----
// EXACT R5 structure (measured 240-246us): 256 threads / 4 waves, QT=64, CTILE=256,
// single-buffer global_load_lds staging with source XOR swizzle, 2 barriers/K-step.
// (Falsified: reg-staged C -44% (R6), QT=128 8-wave -25% (R7), LDS dbuf -5% (R4).)
// Pbf/qsq rows are physical-order; pi output indexed by physical row.
__global__ __launch_bounds__(256, 3) void dist_mfma_kernel(const unsigned short* __restrict__ Pbf,
                                                           const unsigned short* __restrict__ Cbf,
                                                           const float* __restrict__ qsq,
                                                           const float* __restrict__ csq,
                                                           int* __restrict__ pi)
{
    __shared__ __align__(16) short CsS[CTILE * 64];  // 32 KB
    __shared__ __align__(16) short QsS[QT * 64];     //  8 KB
    float* MV = (float*)CsS;                         // merge alias: [64][4][TOPA]
    int*   MI = (int*)(CsS + 4096);                  // 8 KB offset

    const int t    = threadIdx.x;
    const int lane = t & 63;
    const int w    = t >> 6;       // wave 0..3 -> context quarter
    const int l15  = lane & 15;
    const int l4   = lane >> 4;    // 0..3
    const int r8   = lane >> 3;    // 0..7 (staging sub-row)
    const int sc   = lane & 7;     // staging store-chunk
    const int csplit = blockIdx.x;
    const int by = blockIdx.y;
    const int bz = blockIdx.z;
    const int qg0 = bz * NQ + by * QT;

    // loop-invariant lane-relative staging offsets (elements)
    unsigned cOff[8], qOff[2];
    #pragma unroll
    for (int j = 0; j < 8; ++j)
        cOff[j] = (unsigned)((w * 64 + j * 8 + r8) * D_DIM + (sc ^ r8) * 8);
    #pragma unroll
    for (int j = 0; j < 2; ++j)
        qOff[j] = (unsigned)((w * 16 + j * 8 + r8) * D_DIM + (sc ^ r8) * 8);

    float qsv[4];
    #pragma unroll
    for (int s = 0; s < 4; ++s) qsv[s] = qsq[qg0 + s * 16 + l15];

    float bv[4][TOPA]; int bi[4][TOPA];
    #pragma unroll
    for (int s = 0; s < 4; ++s)
        #pragma unroll
        for (int j = 0; j < TOPA; ++j) { bv[s][j] = FLT_MAX; bi[s][j] = 0x7fffffff; }

    const int cpb = NC / CSPLIT;   // 2048
    for (int it = 0; it < cpb / CTILE; ++it) {
        const int cg0 = csplit * cpb + it * CTILE;
        const size_t crow0 = (size_t)bz * NC + cg0;

        f32x4 acc[4][4];
        #pragma unroll
        for (int u = 0; u < 4; ++u)
            #pragma unroll
            for (int s = 0; s < 4; ++s) acc[u][s] = (f32x4)0.0f;

        for (int k0 = 0; k0 < D_DIM; k0 += BK) {
            const unsigned short* cB = Cbf + crow0 * D_DIM + k0;
            const unsigned short* qB = Pbf + (size_t)qg0 * D_DIM + k0;
            __syncthreads();   // all waves done reading previous LDS contents
            #pragma unroll
            for (int j = 0; j < 8; ++j)
                gload16(cB + cOff[j], &CsS[(w * 64 + j * 8) * 64]);
            #pragma unroll
            for (int j = 0; j < 2; ++j)
                gload16(qB + qOff[j], &QsS[(w * 16 + j * 8) * 64]);
            __syncthreads();   // vmcnt drained before barrier -> LDS filled
            #pragma unroll
            for (int ks = 0; ks < 2; ++ks) {
                const int sp = ((ks * 4 + l4) ^ (l15 & 7)) * 8;
                bf16x8 bq[4], ac[4];
                #pragma unroll
                for (int s = 0; s < 4; ++s)
                    bq[s] = *(const bf16x8*)&QsS[(s * 16 + l15) * 64 + sp];
                #pragma unroll
                for (int u = 0; u < 4; ++u)
                    ac[u] = *(const bf16x8*)&CsS[(w * 64 + u * 16 + l15) * 64 + sp];
                #pragma unroll
                for (int u = 0; u < 4; ++u)
                    #pragma unroll
                    for (int s = 0; s < 4; ++s)
                        acc[u][s] = __builtin_amdgcn_mfma_f32_16x16x32_bf16(ac[u], bq[s], acc[u][s], 0, 0, 0);
            }
        }

        // d^2 = |q|^2 + |c|^2 - 2 q.c  -> branchless per-lane register top-5
        #pragma unroll
        for (int u = 0; u < 4; ++u) {
            const int crow = w * 64 + u * 16 + l4 * 4;
            float4 cs4 = *(const float4*)&csq[(size_t)bz * NC + cg0 + crow];
            float csa[4] = {cs4.x, cs4.y, cs4.z, cs4.w};
            #pragma unroll
            for (int s = 0; s < 4; ++s) {
                #pragma unroll
                for (int r = 0; r < 4; ++r) {
                    float v = qsv[s] + csa[r] - 2.0f * acc[u][s][r];
                    ins5b(bv[s], bi[s], v, cg0 + crow + r);
                }
            }
        }
    }

    // wave-level merge across l4 groups (same query columns) via shuffles
    #pragma unroll
    for (int mask = 16; mask <= 32; mask <<= 1) {
        #pragma unroll
        for (int s = 0; s < 4; ++s) {
            float ov[TOPA]; int oi[TOPA];
            #pragma unroll
            for (int j = 0; j < TOPA; ++j) {
                ov[j] = __shfl_xor(bv[s][j], mask, 64);
                oi[j] = __shfl_xor(bi[s][j], mask, 64);
            }
            #pragma unroll
            for (int j = 0; j < TOPA; ++j) insN<TOPA>(bv[s], bi[s], ov[j], oi[j]);
        }
    }
    // cross-wave merge via LDS (l4==0 lanes hold wave-merged lists)
    __syncthreads();
    if (l4 == 0) {
        #pragma unroll
        for (int s = 0; s < 4; ++s) {
            int q = s * 16 + l15;
            #pragma unroll
            for (int j = 0; j < TOPA; ++j) {
                MV[(q * 4 + w) * TOPA + j] = bv[s][j];
                MI[(q * 4 + w) * TOPA + j] = bi[s][j];
            }
        }
    }
    __syncthreads();
    if (t < QT) {
        float mv[TOPA]; int mi[TOPA];
        #pragma unroll
        for (int j = 0; j < TOPA; ++j) { mv[j] = FLT_MAX; mi[j] = 0x7fffffff; }
        for (int l = 0; l < 4; ++l)
            #pragma unroll
            for (int j = 0; j < TOPA; ++j)
                insN<TOPA>(mv, mi, MV[(t * 4 + l) * TOPA + j], MI[(t * 4 + l) * TOPA + j]);
        size_t base = (((size_t)qg0 + t) * CSPLIT + csplit) * TOPA;
        #pragma unroll
        for (int j = 0; j < TOPA; ++j) pi[base + j] = mi[j];
    }
}

// ---- Kernel 5: fp64 exact refine of 40 candidates per query -> top-5, sqrt, outputs ----
// P-row staged ONCE in LDS (was re-read from L2 per candidate: 320KB -> 8KB/block).
// pi and P64 both read at physical row pq (fused-epilogue ordering).
__global__ __launch_bounds__(256) void refine_kernel(const double* __restrict__ P64,
                                                     const int* __restrict__ invperm,
                                                     const float* __restrict__ C,
                                                     const int*   __restrict__ pi,
                                                     float* __restrict__ out)
{
    __shared__ double pS[D_DIM];   // 8 KB staged P-row
    __shared__ double dvs[CAND];
    __shared__ int    dis[CAND];
    const int q    = blockIdx.x;                      // true row
    const int pq   = (q & ~15) | invperm[q & 15];     // physical row (P64, Pbf, pi)
    const int bz   = q >> 10;
    const int t    = threadIdx.x;
    const int wave = t >> 6;
    const int lane = t & 63;
    const double* p = P64 + (size_t)pq * D_DIM;

    #pragma unroll
    for (int j = 0; j < D_DIM / 256; ++j) pS[t + j * 256] = p[t + j * 256];
    __syncthreads();

    for (int k = wave; k < CAND; k += 4) {
        int ci = pi[(size_t)pq * CAND + k];
        const float* c = C + ((size_t)bz * NC + ci) * D_DIM;
        double s = 0.0;
        #pragma unroll
        for (int j = 0; j < 16; ++j) {
            int d = lane + 64 * j;
            double diff = pS[d] - (double)c[d];
            s = fma(diff, diff, s);
        }
        #pragma unroll
        for (int off = 32; off; off >>= 1) s += __shfl_down(s, off, 64);
        if (lane == 0) { dvs[k] = s; dis[k] = ci; }
    }
    __syncthreads();
    if (t == 0) {
        double bv[TOPN]; int bi[TOPN];
        #pragma unroll
        for (int j = 0; j < TOPN; ++j) { bv[j] = DBL_MAX; bi[j] = 0x7fffffff; }
        for (int k = 0; k < CAND; ++k)
            topk_insert<TOPN,double>(bv, bi, dvs[k], dis[k]);
        #pragma unroll
        for (int j = 0; j < TOPN; ++j) {
            out[(size_t)q * TOPN + j] = (float)sqrt(bv[j]);
            out[(size_t)B_DIM * NQ * TOPN + (size_t)q * TOPN + j] = (float)bi[j];
        }
    }
}

extern "C" void kernel_launch(void* const* d_in, const int* in_sizes, int n_in,
                              void* d_out, int out_size, void* d_ws, size_t ws_size,
                              hipStream_t stream) {
    const float* Q    = (const float*)d_in[0];
    const float* C    = (const float*)d_in[1];
    const float* W    = (const float*)d_in[2];
    const float* bias = (const float*)d_in[3];
    float* out = (float*)d_out;

    char* ws = (char*)d_ws;
    double*         P64 = (double*)ws;                                       // 32 MB
    unsigned short* Pbf = (unsigned short*)(ws + (size_t)32 * 1024 * 1024);  //  8 MB
    unsigned short* Cbf = (unsigned short*)(ws + (size_t)40 * 1024 * 1024);  // 128 MB
    float*          qsq = (float*)(ws + (size_t)168 * 1024 * 1024);          // 16 KB
    float*          csq = qsq + 4096;                                        // 256 KB
    int*            pi  = (int*)(csq + 65536);                               // 655 KB
    int*            ivp = pi + (size_t)B_DIM * NQ * CAND;                    // 64 B
    // total ~170 MB of workspace

    hipMemsetAsync(qsq, 0, (size_t)B_DIM * NQ * sizeof(float), stream);  // qsq accumulated by atomics
    proj_packc_kernel<<<PROJ_BLKS + (B_DIM * NC) / 4, 256, 0, stream>>>(Q, W, bias, C, P64, Pbf, qsq, Cbf, csq);
    perm_detect_kernel<<<1, 256, 0, stream>>>(Q, W, bias, P64, ivp);
    dist_mfma_kernel<<<dim3(CSPLIT, NQ / QT, B_DIM), 256, 0, stream>>>(Pbf, Cbf, qsq, csq, pi);
    refine_kernel<<<B_DIM * NQ, 256, 0, stream>>>(P64, ivp, C, pi, out);
}

// Round 10
// 850.982 us; speedup vs baseline: 1.1040x; 1.0078x over previous
//
#include <hip/hip_runtime.h>
#include <cfloat>
#include <math.h>

#define D_DIM 1024
#define B_DIM 4
#define NQ    1024
#define NC    16384
#define TOPN  5
#define TOPA  5               // stage-A candidates per context split
#define CSPLIT 8              // context splits per batch
#define CAND  (TOPA*CSPLIT)   // 40 candidates per query
#define QT    64              // queries per block (dist kernel)
#define CTILE 256             // contexts per tile iteration (dist kernel)
#define BK    64              // K per LDS stage (bf16 elements)
#define NSTEP (D_DIM/BK)      // 16

// proj (fp64 MFMA) tiling
#define PBM 128
#define PBN 64
#define PBK 32
#define PPAD 4
#define PROJ_BLKS ((D_DIM/PBN) * ((B_DIM*NQ)/PBM))   // 512

typedef __bf16 bf16x8 __attribute__((ext_vector_type(8)));
typedef float  f32x4  __attribute__((ext_vector_type(4)));
typedef double f64x4  __attribute__((ext_vector_type(4)));

__device__ __forceinline__ unsigned short f2bf(float f) {
    unsigned u = __builtin_bit_cast(unsigned, f);
    unsigned r = (u + 0x7fffu + ((u >> 16) & 1u)) >> 16;
    return (unsigned short)r;
}

// async global->LDS, 16B per lane; LDS dest = wave-uniform base + lane*16
__device__ __forceinline__ void gload16(const void* g, void* l) {
    __builtin_amdgcn_global_load_lds(
        (const __attribute__((address_space(1))) unsigned*)g,
        (__attribute__((address_space(3))) unsigned*)l, 16, 0, 0);
}

// ---- lexicographic (value, index) top-N insert (used by fp64 refine) ----
template<int N, typename T>
__device__ __forceinline__ void topk_insert(T (&bv)[N], int (&bi)[N], T v, int ci) {
    if (v < bv[N-1] || (v == bv[N-1] && ci < bi[N-1])) {
        bv[N-1] = v; bi[N-1] = ci;
        #pragma unroll
        for (int s = N-1; s > 0; --s) {
            bool sw = (bv[s] < bv[s-1]) || (bv[s] == bv[s-1] && bi[s] < bi[s-1]);
            if (sw) {
                T tv = bv[s-1]; bv[s-1] = bv[s]; bv[s] = tv;
                int ti = bi[s-1]; bi[s-1] = bi[s]; bi[s] = ti;
            }
        }
    }
}

// ---- value-only top-N insert (merge phases; ties resolved by fp64 refine) ----
template<int N>
__device__ __forceinline__ void insN(float (&bv)[N], int (&bi)[N], float v, int ci) {
    if (v < bv[N-1]) {
        bv[N-1] = v; bi[N-1] = ci;
        #pragma unroll
        for (int s = N-1; s > 0; --s) {
            if (bv[s] < bv[s-1]) {
                float tv = bv[s-1]; bv[s-1] = bv[s]; bv[s] = tv;
                int   ti = bi[s-1]; bi[s-1] = bi[s]; bi[s] = ti;
            }
        }
    }
}

// ---- branchless sorted (value,index) top-5 insert for the hot acc drain ----
__device__ __forceinline__ void ins5b(float (&bv)[TOPA], int (&bi)[TOPA], float v, int ci) {
    #pragma unroll
    for (int s = 0; s < TOPA; ++s) {
        const bool  c    = v < bv[s];
        const float vmin = c ? v : bv[s];
        const float vmax = c ? bv[s] : v;
        const int   imin = c ? ci : bi[s];
        const int   imax = c ? bi[s] : ci;
        bv[s] = vmin; bi[s] = imin;
        v = vmax; ci = imax;
    }
}

// ---- Kernel 1 (fat): blocks [0,512) = fp64-MFMA projection (+ fused pack_q
// epilogue); rest = pack C.  Pbf/qsq/pi are PHYSICAL-row ordered; refine reads
// via invperm -- correct for ANY within-16 row perm of the f64 MFMA.
__global__ __launch_bounds__(256) void proj_packc_kernel(const float* __restrict__ Q,
                                                         const float* __restrict__ W,
                                                         const float* __restrict__ bias,
                                                         const float* __restrict__ C,
                                                         double* __restrict__ P64,
                                                         unsigned short* __restrict__ Pbf,
                                                         float* __restrict__ qsq,
                                                         unsigned short* __restrict__ Cbf,
                                                         float* __restrict__ csq)
{
    const int bid = blockIdx.x;
    if (bid >= PROJ_BLKS) {
        // ---------------- pack_c branch ----------------
        int wave = threadIdx.x >> 6;
        int lane = threadIdx.x & 63;
        int row  = (bid - PROJ_BLKS) * 4 + wave;
        const float* x = C + (size_t)row * D_DIM;
        float s = 0.f;
        #pragma unroll
        for (int i = 0; i < 4; ++i) {
            float4 v = *(const float4*)&x[lane * 4 + i * 256];
            s += v.x * v.x + v.y * v.y + v.z * v.z + v.w * v.w;
            ushort4 h;
            h.x = f2bf(v.x); h.y = f2bf(v.y); h.z = f2bf(v.z); h.w = f2bf(v.w);
            *(ushort4*)&Cbf[(size_t)row * D_DIM + lane * 4 + i * 256] = h;
        }
        #pragma unroll
        for (int off = 32; off; off >>= 1) s += __shfl_down(s, off, 64);
        if (lane == 0) csq[row] = s;
        return;
    }
    // ---------------- proj branch ----------------
    __shared__ __align__(16) float Qs[PBM][PBK + PPAD];   // 18 KB
    __shared__ __align__(16) float Ws[PBN][PBK + PPAD];   //  9 KB

    const int t    = threadIdx.x;
    const int lane = t & 63;
    const int w    = t >> 6;          // wave 0..3
    const int l15  = lane & 15;
    const int l4   = lane >> 4;       // 0..3
    const int m0   = (bid >> 4) * PBM;
    const int n0   = (bid & 15) * PBN;
    const int wm   = (w >> 1) * 64;   // wave row offset in tile
    const int wn   = (w & 1) * 32;    // wave col offset in tile

    const int srow = t >> 3;          // 0..31 staging row
    const int scol = (t & 7) * 4;     // staging float4 col (0..28)

    f64x4 acc[4][2];
    #pragma unroll
    for (int fm = 0; fm < 4; ++fm)
        #pragma unroll
        for (int fn = 0; fn < 2; ++fn) acc[fm][fn] = (f64x4)0.0;

    for (int k0 = 0; k0 < D_DIM; k0 += PBK) {
        float4 qa0 = *(const float4*)&Q[(size_t)(m0 + srow)      * D_DIM + k0 + scol];
        float4 qa1 = *(const float4*)&Q[(size_t)(m0 + srow + 32) * D_DIM + k0 + scol];
        float4 qa2 = *(const float4*)&Q[(size_t)(m0 + srow + 64) * D_DIM + k0 + scol];
        float4 qa3 = *(const float4*)&Q[(size_t)(m0 + srow + 96) * D_DIM + k0 + scol];
        float4 wa0 = *(const float4*)&W[(size_t)(n0 + srow)      * D_DIM + k0 + scol];
        float4 wa1 = *(const float4*)&W[(size_t)(n0 + srow + 32) * D_DIM + k0 + scol];
        __syncthreads();   // previous-iteration readers done
        *(float4*)&Qs[srow][scol]      = qa0;
        *(float4*)&Qs[srow + 32][scol] = qa1;
        *(float4*)&Qs[srow + 64][scol] = qa2;
        *(float4*)&Qs[srow + 96][scol] = qa3;
        *(float4*)&Ws[srow][scol]      = wa0;
        *(float4*)&Ws[srow + 32][scol] = wa1;
        __syncthreads();   // tile visible to all waves

        #pragma unroll
        for (int ks = 0; ks < PBK / 4; ++ks) {
            const int kc = ks * 4 + l4;
            double a[4], b[2];
            #pragma unroll
            for (int fm = 0; fm < 4; ++fm) a[fm] = (double)Qs[wm + fm * 16 + l15][kc];
            #pragma unroll
            for (int fn = 0; fn < 2; ++fn) b[fn] = (double)Ws[wn + fn * 16 + l15][kc];
            #pragma unroll
            for (int fm = 0; fm < 4; ++fm)
                #pragma unroll
                for (int fn = 0; fn < 2; ++fn)
                    acc[fm][fn] = __builtin_amdgcn_mfma_f64_16x16x4f64(a[fm], b[fn], acc[fm][fn], 0, 0, 0);
        }
    }

    // fused epilogue: P64 + bf16 Pbf + fp32 qsq (16-lane reduce + atomicAdd)
    #pragma unroll
    for (int fm = 0; fm < 4; ++fm) {
        #pragma unroll
        for (int j = 0; j < 4; ++j) {
            const int row = m0 + wm + fm * 16 + j * 4 + l4;   // physical row
            float part = 0.f;
            #pragma unroll
            for (int fn = 0; fn < 2; ++fn) {
                const int col = n0 + wn + fn * 16 + l15;
                double d = acc[fm][fn][j] + (double)bias[col];
                P64[(size_t)row * D_DIM + col] = d;
                float a = (float)d;
                part += a * a;
                Pbf[(size_t)row * D_DIM + col] = f2bf(a);
            }
            #pragma unroll
            for (int m = 1; m < 16; m <<= 1) part += __shfl_xor(part, m, 64);
            if (l15 == 0) atomicAdd(&qsq[row], part);
        }
    }
}

// ---- Kernel 1b: measure the actual within-16 row permutation of P64 ----
__global__ __launch_bounds__(256) void perm_detect_kernel(const float* __restrict__ Q,
                                                          const float* __restrict__ W,
                                                          const float* __restrict__ bias,
                                                          const double* __restrict__ P64,
                                                          int* __restrict__ invperm)
{
    __shared__ double tv[16];
    const int t = threadIdx.x;      // 256 threads
    const int g = t >> 4;           // true row 0..15
    const int s = t & 15;           // k-slice
    if (t < 16) invperm[t] = t;     // identity default (overwritten below)

    double acc = 0.0;
    const int kb = s * 64;
    for (int k = 0; k < 64; ++k)
        acc = fma((double)Q[(size_t)g * D_DIM + kb + k], (double)W[kb + k], acc);
    #pragma unroll
    for (int off = 8; off; off >>= 1) acc += __shfl_down(acc, off, 16);
    if (s == 0) tv[g] = acc + (double)bias[0];
    __syncthreads();

    if (t < 16) {
        double p = P64[(size_t)t * D_DIM];   // physical row t, col 0
        int best = 0; double bd = fabs(p - tv[0]);
        #pragma unroll
        for (int i = 1; i < 16; ++i) {
            double d = fabs(p - tv[i]);
            if (d < bd) { bd = d; best = i; }
        }
        invperm[best] = t;   // physical row t holds true row `best`
    }
}

// ---- Kernel 4: bf16-MFMA screening GEMM + per-lane register top-5 ----
// R10: counted-vmcnt pipeline (T4). Double-buffered LDS (80 KB, still 2 blk/CU
// = the grid's actual occupancy). Per K-step: issue 10 gload_lds for step g+1,
// then `s_waitcnt vmcnt(10)` (step g's loads landed, g+1's stay in flight
// ACROSS the barrier) + raw s_barrier; compute; raw s_barrier. Removes the
// vmcnt(0) drain that held both pipes at <32% (R9 counters).
// Race analysis: buffer b is overwritten only after the barrier that follows
// the compute which last read it; per-wave vmcnt(10)+barrier => all waves'
// current-step loads landed before any ds_read of them; the per-tile csq load
// only makes vmcnt(10) conservative (it is older than the staged loads).
__global__ __launch_bounds__(256, 2) void dist_mfma_kernel(const unsigned short* __restrict__ Pbf,
                                                           const unsigned short* __restrict__ Cbf,
                                                           const float* __restrict__ qsq,
                                                           const float* __restrict__ csq,
                                                           int* __restrict__ pi)
{
    __shared__ __align__(16) short CsS[2][CTILE * 64];  // 64 KB
    __shared__ __align__(16) short QsS[2][QT * 64];     // 16 KB
    float* MV = (float*)&CsS[0][0];                     // merge alias: [64][4][TOPA]
    int*   MI = (int*)&CsS[0][4096];                    // 8 KB offset

    const int t    = threadIdx.x;
    const int lane = t & 63;
    const int w    = t >> 6;       // wave 0..3 -> context quarter
    const int l15  = lane & 15;
    const int l4   = lane >> 4;    // 0..3
    const int r8   = lane >> 3;    // 0..7 (staging sub-row)
    const int sc   = lane & 7;     // staging store-chunk
    const int csplit = blockIdx.x;
    const int by = blockIdx.y;
    const int bz = blockIdx.z;
    const int qg0 = bz * NQ + by * QT;
    const int cpb = NC / CSPLIT;   // 2048
    const int cgb = csplit * cpb;
    const int nIt = cpb / CTILE;   // 8

    // loop-invariant lane-relative staging offsets (elements)
    unsigned cOff[8], qOff[2];
    #pragma unroll
    for (int j = 0; j < 8; ++j)
        cOff[j] = (unsigned)((w * 64 + j * 8 + r8) * D_DIM + (sc ^ r8) * 8);
    #pragma unroll
    for (int j = 0; j < 2; ++j)
        qOff[j] = (unsigned)((w * 16 + j * 8 + r8) * D_DIM + (sc ^ r8) * 8);

    const unsigned short* cBase = Cbf + ((size_t)bz * NC + cgb) * D_DIM;
    const unsigned short* qBase = Pbf + (size_t)qg0 * D_DIM;

    float qsv[4];
    #pragma unroll
    for (int s = 0; s < 4; ++s) qsv[s] = qsq[qg0 + s * 16 + l15];

    float bv[4][TOPA]; int bi[4][TOPA];
    #pragma unroll
    for (int s = 0; s < 4; ++s)
        #pragma unroll
        for (int j = 0; j < TOPA; ++j) { bv[s][j] = FLT_MAX; bi[s][j] = 0x7fffffff; }

    // stage K-chunk (it, kk) into buffer b: 10 x global_load_lds per wave
    auto stage = [&](int it, int kk, int b) {
        const unsigned short* cB = cBase + (size_t)(it * CTILE) * D_DIM + kk * BK;
        const unsigned short* qB = qBase + kk * BK;
        #pragma unroll
        for (int j = 0; j < 8; ++j)
            gload16(cB + cOff[j], &CsS[b][(w * 64 + j * 8) * 64]);
        #pragma unroll
        for (int j = 0; j < 2; ++j)
            gload16(qB + qOff[j], &QsS[b][(w * 16 + j * 8) * 64]);
    };

    stage(0, 0, 0);
    int cur = 0;

    for (int it = 0; it < nIt; ++it) {
        const int cg0 = cgb + it * CTILE;

        f32x4 acc[4][4];
        #pragma unroll
        for (int u = 0; u < 4; ++u)
            #pragma unroll
            for (int s = 0; s < 4; ++s) acc[u][s] = (f32x4)0.0f;

        for (int kk = 0; kk < NSTEP; ++kk) {
            if (it == nIt - 1 && kk == NSTEP - 1) {
                // last step: no prefetch, full drain of own loads
                __builtin_amdgcn_sched_barrier(0);
                asm volatile("s_waitcnt vmcnt(0)\n\ts_barrier" ::: "memory");
            } else {
                int nk = kk + 1, nit = it;
                if (nk == NSTEP) { nk = 0; ++nit; }
                stage(nit, nk, cur ^ 1);           // issue next-step loads FIRST
                __builtin_amdgcn_sched_barrier(0); // pin issue above the wait
                // own 10 current-step loads are the oldest -> landed at vmcnt(10)
                asm volatile("s_waitcnt vmcnt(10)\n\ts_barrier" ::: "memory");
            }
            #pragma unroll
            for (int ks = 0; ks < 2; ++ks) {
                const int sp = ((ks * 4 + l4) ^ (l15 & 7)) * 8;
                bf16x8 bq[4], ac[4];
                #pragma unroll
                for (int s = 0; s < 4; ++s)
                    bq[s] = *(const bf16x8*)&QsS[cur][(s * 16 + l15) * 64 + sp];
                #pragma unroll
                for (int u = 0; u < 4; ++u)
                    ac[u] = *(const bf16x8*)&CsS[cur][(w * 64 + u * 16 + l15) * 64 + sp];
                #pragma unroll
                for (int u = 0; u < 4; ++u)
                    #pragma unroll
                    for (int s = 0; s < 4; ++s)
                        acc[u][s] = __builtin_amdgcn_mfma_f32_16x16x32_bf16(ac[u], bq[s], acc[u][s], 0, 0, 0);
            }
            // all ds_reads of buf cur consumed above (lgkmcnt waits precede MFMA use)
            asm volatile("s_barrier" ::: "memory");
            cur ^= 1;
        }

        // d^2 = |q|^2 + |c|^2 - 2 q.c  -> branchless per-lane register top-5
        #pragma unroll
        for (int u = 0; u < 4; ++u) {
            const int crow = w * 64 + u * 16 + l4 * 4;
            float4 cs4 = *(const float4*)&csq[(size_t)bz * NC + cg0 + crow];
            float csa[4] = {cs4.x, cs4.y, cs4.z, cs4.w};
            #pragma unroll
            for (int s = 0; s < 4; ++s) {
                #pragma unroll
                for (int r = 0; r < 4; ++r) {
                    float v = qsv[s] + csa[r] - 2.0f * acc[u][s][r];
                    ins5b(bv[s], bi[s], v, cg0 + crow + r);
                }
            }
        }
    }

    // wave-level merge across l4 groups (same query columns) via shuffles
    #pragma unroll
    for (int mask = 16; mask <= 32; mask <<= 1) {
        #pragma unroll
        for (int s = 0; s < 4; ++s) {
            float ov[TOPA]; int oi[TOPA];
            #pragma unroll
            for (int j = 0; j < TOPA; ++j) {
                ov[j] = __shfl_xor(bv[s][j], mask, 64);
                oi[j] = __shfl_xor(bi[s][j], mask, 64);
            }
            #pragma unroll
            for (int j = 0; j < TOPA; ++j) insN<TOPA>(bv[s], bi[s], ov[j], oi[j]);
        }
    }
    // cross-wave merge via LDS (l4==0 lanes hold wave-merged lists)
    __syncthreads();
    if (l4 == 0) {
        #pragma unroll
        for (int s = 0; s < 4; ++s) {
            int q = s * 16 + l15;
            #pragma unroll
            for (int j = 0; j < TOPA; ++j) {
                MV[(q * 4 + w) * TOPA + j] = bv[s][j];
                MI[(q * 4 + w) * TOPA + j] = bi[s][j];
            }
        }
    }
    __syncthreads();
    if (t < QT) {
        float mv[TOPA]; int mi[TOPA];
        #pragma unroll
        for (int j = 0; j < TOPA; ++j) { mv[j] = FLT_MAX; mi[j] = 0x7fffffff; }
        for (int l = 0; l < 4; ++l)
            #pragma unroll
            for (int j = 0; j < TOPA; ++j)
                insN<TOPA>(mv, mi, MV[(t * 4 + l) * TOPA + j], MI[(t * 4 + l) * TOPA + j]);
        size_t base = (((size_t)qg0 + t) * CSPLIT + csplit) * TOPA;
        #pragma unroll
        for (int j = 0; j < TOPA; ++j) pi[base + j] = mi[j];
    }
}

// ---- Kernel 5: fp64 exact refine of 40 candidates per query -> top-5, sqrt, outputs ----
__global__ __launch_bounds__(256) void refine_kernel(const double* __restrict__ P64,
                                                     const int* __restrict__ invperm,
                                                     const float* __restrict__ C,
                                                     const int*   __restrict__ pi,
                                                     float* __restrict__ out)
{
    __shared__ double pS[D_DIM];   // 8 KB staged P-row
    __shared__ double dvs[CAND];
    __shared__ int    dis[CAND];
    const int q    = blockIdx.x;                      // true row
    const int pq   = (q & ~15) | invperm[q & 15];     // physical row (P64, Pbf, pi)
    const int bz   = q >> 10;
    const int t    = threadIdx.x;
    const int wave = t >> 6;
    const int lane = t & 63;
    const double* p = P64 + (size_t)pq * D_DIM;

    #pragma unroll
    for (int j = 0; j < D_DIM / 256; ++j) pS[t + j * 256] = p[t + j * 256];
    __syncthreads();

    for (int k = wave; k < CAND; k += 4) {
        int ci = pi[(size_t)pq * CAND + k];
        const float* c = C + ((size_t)bz * NC + ci) * D_DIM;
        double s = 0.0;
        #pragma unroll
        for (int j = 0; j < 16; ++j) {
            int d = lane + 64 * j;
            double diff = pS[d] - (double)c[d];
            s = fma(diff, diff, s);
        }
        #pragma unroll
        for (int off = 32; off; off >>= 1) s += __shfl_down(s, off, 64);
        if (lane == 0) { dvs[k] = s; dis[k] = ci; }
    }
    __syncthreads();
    if (t == 0) {
        double bv[TOPN]; int bi[TOPN];
        #pragma unroll
        for (int j = 0; j < TOPN; ++j) { bv[j] = DBL_MAX; bi[j] = 0x7fffffff; }
        for (int k = 0; k < CAND; ++k)
            topk_insert<TOPN,double>(bv, bi, dvs[k], dis[k]);
        #pragma unroll
        for (int j = 0; j < TOPN; ++j) {
            out[(size_t)q * TOPN + j] = (float)sqrt(bv[j]);
            out[(size_t)B_DIM * NQ * TOPN + (size_t)q * TOPN + j] = (float)bi[j];
        }
    }
}

extern "C" void kernel_launch(void* const* d_in, const int* in_sizes, int n_in,
                              void* d_out, int out_size, void* d_ws, size_t ws_size,
                              hipStream_t stream) {
    const float* Q    = (const float*)d_in[0];
    const float* C    = (const float*)d_in[1];
    const float* W    = (const float*)d_in[2];
    const float* bias = (const float*)d_in[3];
    float* out = (float*)d_out;

    char* ws = (char*)d_ws;
    double*         P64 = (double*)ws;                                       // 32 MB
    unsigned short* Pbf = (unsigned short*)(ws + (size_t)32 * 1024 * 1024);  //  8 MB
    unsigned short* Cbf = (unsigned short*)(ws + (size_t)40 * 1024 * 1024);  // 128 MB
    float*          qsq = (float*)(ws + (size_t)168 * 1024 * 1024);          // 16 KB
    float*          csq = qsq + 4096;                                        // 256 KB
    int*            pi  = (int*)(csq + 65536);                               // 655 KB
    int*            ivp = pi + (size_t)B_DIM * NQ * CAND;                    // 64 B
    // total ~170 MB of workspace

    hipMemsetAsync(qsq, 0, (size_t)B_DIM * NQ * sizeof(float), stream);  // qsq accumulated by atomics
    proj_packc_kernel<<<PROJ_BLKS + (B_DIM * NC) / 4, 256, 0, stream>>>(Q, W, bias, C, P64, Pbf, qsq, Cbf, csq);
    perm_detect_kernel<<<1, 256, 0, stream>>>(Q, W, bias, P64, ivp);
    dist_mfma_kernel<<<dim3(CSPLIT, NQ / QT, B_DIM), 256, 0, stream>>>(Pbf, Cbf, qsq, csq, pi);
    refine_kernel<<<B_DIM * NQ, 256, 0, stream>>>(P64, ivp, C, pi, out);
}

// Round 11
// 838.214 us; speedup vs baseline: 1.1208x; 1.0152x over previous
//
#include <hip/hip_runtime.h>
#include <cfloat>
#include <math.h>

#define D_DIM 1024
#define B_DIM 4
#define NQ    1024
#define NC    16384
#define TOPN  5
#define TOPA  5               // stage-A candidates per context split
#define CSPLIT 8              // context splits per batch
#define CAND  (TOPA*CSPLIT)   // 40 candidates per query
#define QT    64              // queries per block (dist kernel)
#define CTILE 512             // contexts per tile iteration (R11: 256->512, 128 c/wave)
#define BK    64              // K per LDS stage (bf16 elements)
#define NSTEP (D_DIM/BK)      // 16

// proj (fp64 MFMA) tiling
#define PBM 128
#define PBN 64
#define PBK 32
#define PPAD 4
#define PROJ_BLKS ((D_DIM/PBN) * ((B_DIM*NQ)/PBM))   // 512

typedef __bf16 bf16x8 __attribute__((ext_vector_type(8)));
typedef float  f32x4  __attribute__((ext_vector_type(4)));
typedef double f64x4  __attribute__((ext_vector_type(4)));

__device__ __forceinline__ unsigned short f2bf(float f) {
    unsigned u = __builtin_bit_cast(unsigned, f);
    unsigned r = (u + 0x7fffu + ((u >> 16) & 1u)) >> 16;
    return (unsigned short)r;
}

// async global->LDS, 16B per lane; LDS dest = wave-uniform base + lane*16
__device__ __forceinline__ void gload16(const void* g, void* l) {
    __builtin_amdgcn_global_load_lds(
        (const __attribute__((address_space(1))) unsigned*)g,
        (__attribute__((address_space(3))) unsigned*)l, 16, 0, 0);
}

// ---- lexicographic (value, index) top-N insert (used by fp64 refine) ----
template<int N, typename T>
__device__ __forceinline__ void topk_insert(T (&bv)[N], int (&bi)[N], T v, int ci) {
    if (v < bv[N-1] || (v == bv[N-1] && ci < bi[N-1])) {
        bv[N-1] = v; bi[N-1] = ci;
        #pragma unroll
        for (int s = N-1; s > 0; --s) {
            bool sw = (bv[s] < bv[s-1]) || (bv[s] == bv[s-1] && bi[s] < bi[s-1]);
            if (sw) {
                T tv = bv[s-1]; bv[s-1] = bv[s]; bv[s] = tv;
                int ti = bi[s-1]; bi[s-1] = bi[s]; bi[s] = ti;
            }
        }
    }
}

// ---- value-only top-N insert (merge phases; ties resolved by fp64 refine) ----
template<int N>
__device__ __forceinline__ void insN(float (&bv)[N], int (&bi)[N], float v, int ci) {
    if (v < bv[N-1]) {
        bv[N-1] = v; bi[N-1] = ci;
        #pragma unroll
        for (int s = N-1; s > 0; --s) {
            if (bv[s] < bv[s-1]) {
                float tv = bv[s-1]; bv[s-1] = bv[s]; bv[s] = tv;
                int   ti = bi[s-1]; bi[s-1] = bi[s]; bi[s] = ti;
            }
        }
    }
}

// ---- branchless sorted (value,index) top-5 insert for the hot acc drain ----
__device__ __forceinline__ void ins5b(float (&bv)[TOPA], int (&bi)[TOPA], float v, int ci) {
    #pragma unroll
    for (int s = 0; s < TOPA; ++s) {
        const bool  c    = v < bv[s];
        const float vmin = c ? v : bv[s];
        const float vmax = c ? bv[s] : v;
        const int   imin = c ? ci : bi[s];
        const int   imax = c ? bi[s] : ci;
        bv[s] = vmin; bi[s] = imin;
        v = vmax; ci = imax;
    }
}

// ---- Kernel 1 (fat): blocks [0,512) = fp64-MFMA projection (+ fused pack_q
// epilogue); rest = pack C.  Pbf/qsq/pi are PHYSICAL-row ordered; refine reads
// via invperm -- correct for ANY within-16 row perm of the f64 MFMA.
__global__ __launch_bounds__(256) void proj_packc_kernel(const float* __restrict__ Q,
                                                         const float* __restrict__ W,
                                                         const float* __restrict__ bias,
                                                         const float* __restrict__ C,
                                                         double* __restrict__ P64,
                                                         unsigned short* __restrict__ Pbf,
                                                         float* __restrict__ qsq,
                                                         unsigned short* __restrict__ Cbf,
                                                         float* __restrict__ csq)
{
    const int bid = blockIdx.x;
    if (bid >= PROJ_BLKS) {
        // ---------------- pack_c branch ----------------
        int wave = threadIdx.x >> 6;
        int lane = threadIdx.x & 63;
        int row  = (bid - PROJ_BLKS) * 4 + wave;
        const float* x = C + (size_t)row * D_DIM;
        float s = 0.f;
        #pragma unroll
        for (int i = 0; i < 4; ++i) {
            float4 v = *(const float4*)&x[lane * 4 + i * 256];
            s += v.x * v.x + v.y * v.y + v.z * v.z + v.w * v.w;
            ushort4 h;
            h.x = f2bf(v.x); h.y = f2bf(v.y); h.z = f2bf(v.z); h.w = f2bf(v.w);
            *(ushort4*)&Cbf[(size_t)row * D_DIM + lane * 4 + i * 256] = h;
        }
        #pragma unroll
        for (int off = 32; off; off >>= 1) s += __shfl_down(s, off, 64);
        if (lane == 0) csq[row] = s;
        return;
    }
    // ---------------- proj branch ----------------
    __shared__ __align__(16) float Qs[PBM][PBK + PPAD];   // 18 KB
    __shared__ __align__(16) float Ws[PBN][PBK + PPAD];   //  9 KB

    const int t    = threadIdx.x;
    const int lane = t & 63;
    const int w    = t >> 6;          // wave 0..3
    const int l15  = lane & 15;
    const int l4   = lane >> 4;       // 0..3
    const int m0   = (bid >> 4) * PBM;
    const int n0   = (bid & 15) * PBN;
    const int wm   = (w >> 1) * 64;   // wave row offset in tile
    const int wn   = (w & 1) * 32;    // wave col offset in tile

    const int srow = t >> 3;          // 0..31 staging row
    const int scol = (t & 7) * 4;     // staging float4 col (0..28)

    f64x4 acc[4][2];
    #pragma unroll
    for (int fm = 0; fm < 4; ++fm)
        #pragma unroll
        for (int fn = 0; fn < 2; ++fn) acc[fm][fn] = (f64x4)0.0;

    for (int k0 = 0; k0 < D_DIM; k0 += PBK) {
        float4 qa0 = *(const float4*)&Q[(size_t)(m0 + srow)      * D_DIM + k0 + scol];
        float4 qa1 = *(const float4*)&Q[(size_t)(m0 + srow + 32) * D_DIM + k0 + scol];
        float4 qa2 = *(const float4*)&Q[(size_t)(m0 + srow + 64) * D_DIM + k0 + scol];
        float4 qa3 = *(const float4*)&Q[(size_t)(m0 + srow + 96) * D_DIM + k0 + scol];
        float4 wa0 = *(const float4*)&W[(size_t)(n0 + srow)      * D_DIM + k0 + scol];
        float4 wa1 = *(const float4*)&W[(size_t)(n0 + srow + 32) * D_DIM + k0 + scol];
        __syncthreads();   // previous-iteration readers done
        *(float4*)&Qs[srow][scol]      = qa0;
        *(float4*)&Qs[srow + 32][scol] = qa1;
        *(float4*)&Qs[srow + 64][scol] = qa2;
        *(float4*)&Qs[srow + 96][scol] = qa3;
        *(float4*)&Ws[srow][scol]      = wa0;
        *(float4*)&Ws[srow + 32][scol] = wa1;
        __syncthreads();   // tile visible to all waves

        #pragma unroll
        for (int ks = 0; ks < PBK / 4; ++ks) {
            const int kc = ks * 4 + l4;
            double a[4], b[2];
            #pragma unroll
            for (int fm = 0; fm < 4; ++fm) a[fm] = (double)Qs[wm + fm * 16 + l15][kc];
            #pragma unroll
            for (int fn = 0; fn < 2; ++fn) b[fn] = (double)Ws[wn + fn * 16 + l15][kc];
            #pragma unroll
            for (int fm = 0; fm < 4; ++fm)
                #pragma unroll
                for (int fn = 0; fn < 2; ++fn)
                    acc[fm][fn] = __builtin_amdgcn_mfma_f64_16x16x4f64(a[fm], b[fn], acc[fm][fn], 0, 0, 0);
        }
    }

    // fused epilogue: P64 + bf16 Pbf + fp32 qsq (16-lane reduce + atomicAdd)
    #pragma unroll
    for (int fm = 0; fm < 4; ++fm) {
        #pragma unroll
        for (int j = 0; j < 4; ++j) {
            const int row = m0 + wm + fm * 16 + j * 4 + l4;   // physical row
            float part = 0.f;
            #pragma unroll
            for (int fn = 0; fn < 2; ++fn) {
                const int col = n0 + wn + fn * 16 + l15;
                double d = acc[fm][fn][j] + (double)bias[col];
                P64[(size_t)row * D_DIM + col] = d;
                float a = (float)d;
                part += a * a;
                Pbf[(size_t)row * D_DIM + col] = f2bf(a);
            }
            #pragma unroll
            for (int m = 1; m < 16; m <<= 1) part += __shfl_xor(part, m, 64);
            if (l15 == 0) atomicAdd(&qsq[row], part);
        }
    }
}

// ---- Kernel 1b: measure the actual within-16 row permutation of P64 ----
__global__ __launch_bounds__(256) void perm_detect_kernel(const float* __restrict__ Q,
                                                          const float* __restrict__ W,
                                                          const float* __restrict__ bias,
                                                          const double* __restrict__ P64,
                                                          int* __restrict__ invperm)
{
    __shared__ double tv[16];
    const int t = threadIdx.x;      // 256 threads
    const int g = t >> 4;           // true row 0..15
    const int s = t & 15;           // k-slice
    if (t < 16) invperm[t] = t;     // identity default (overwritten below)

    double acc = 0.0;
    const int kb = s * 64;
    for (int k = 0; k < 64; ++k)
        acc = fma((double)Q[(size_t)g * D_DIM + kb + k], (double)W[kb + k], acc);
    #pragma unroll
    for (int off = 8; off; off >>= 1) acc += __shfl_down(acc, off, 16);
    if (s == 0) tv[g] = acc + (double)bias[0];
    __syncthreads();

    if (t < 16) {
        double p = P64[(size_t)t * D_DIM];   // physical row t, col 0
        int best = 0; double bd = fabs(p - tv[0]);
        #pragma unroll
        for (int i = 1; i < 16; ++i) {
            double d = fabs(p - tv[i]);
            if (d < bd) { bd = d; best = i; }
        }
        invperm[best] = t;   // physical row t holds true row `best`
    }
}

// ---- Kernel 4: bf16-MFMA screening GEMM + per-lane register top-5 ----
// R11: 128 contexts per wave (8x4 fragment tile) -> per ks: 12 ds_read_b128
// feed 32 MFMA (2.67 MFMA/read vs 2.0), CTILE=512 halves K-step/barrier count.
// Single-buffer 2-barrier staging (R5 structure; counted-vmcnt was neutral R10,
// reg-staging -44% R6, 8-wave -25% R7). acc[8][4] f32x4; launch_bounds(256,2).
__global__ __launch_bounds__(256, 2) void dist_mfma_kernel(const unsigned short* __restrict__ Pbf,
                                                           const unsigned short* __restrict__ Cbf,
                                                           const float* __restrict__ qsq,
                                                           const float* __restrict__ csq,
                                                           int* __restrict__ pi)
{
    __shared__ __align__(16) short CsS[CTILE * 64];  // 64 KB
    __shared__ __align__(16) short QsS[QT * 64];     //  8 KB
    float* MV = (float*)CsS;                         // merge alias: [64][4][TOPA]
    int*   MI = (int*)(CsS + 4096);                  // 8 KB offset

    const int t    = threadIdx.x;
    const int lane = t & 63;
    const int w    = t >> 6;       // wave 0..3 -> 128-context strip
    const int l15  = lane & 15;
    const int l4   = lane >> 4;    // 0..3
    const int r8   = lane >> 3;    // 0..7 (staging sub-row)
    const int sc   = lane & 7;     // staging store-chunk
    const int csplit = blockIdx.x;
    const int by = blockIdx.y;
    const int bz = blockIdx.z;
    const int qg0 = bz * NQ + by * QT;

    // loop-invariant lane-relative staging offsets (elements)
    unsigned cOff[16], qOff[2];
    #pragma unroll
    for (int j = 0; j < 16; ++j)
        cOff[j] = (unsigned)((w * 128 + j * 8 + r8) * D_DIM + (sc ^ r8) * 8);
    #pragma unroll
    for (int j = 0; j < 2; ++j)
        qOff[j] = (unsigned)((w * 16 + j * 8 + r8) * D_DIM + (sc ^ r8) * 8);

    float qsv[4];
    #pragma unroll
    for (int s = 0; s < 4; ++s) qsv[s] = qsq[qg0 + s * 16 + l15];

    float bv[4][TOPA]; int bi[4][TOPA];
    #pragma unroll
    for (int s = 0; s < 4; ++s)
        #pragma unroll
        for (int j = 0; j < TOPA; ++j) { bv[s][j] = FLT_MAX; bi[s][j] = 0x7fffffff; }

    const int cpb = NC / CSPLIT;   // 2048
    for (int it = 0; it < cpb / CTILE; ++it) {       // 4 iterations
        const int cg0 = csplit * cpb + it * CTILE;
        const size_t crow0 = (size_t)bz * NC + cg0;

        f32x4 acc[8][4];
        #pragma unroll
        for (int u = 0; u < 8; ++u)
            #pragma unroll
            for (int s = 0; s < 4; ++s) acc[u][s] = (f32x4)0.0f;

        for (int k0 = 0; k0 < D_DIM; k0 += BK) {
            const unsigned short* cB = Cbf + crow0 * D_DIM + k0;
            const unsigned short* qB = Pbf + (size_t)qg0 * D_DIM + k0;
            __syncthreads();   // all waves done reading previous LDS contents
            #pragma unroll
            for (int j = 0; j < 16; ++j)
                gload16(cB + cOff[j], &CsS[(w * 128 + j * 8) * 64]);
            #pragma unroll
            for (int j = 0; j < 2; ++j)
                gload16(qB + qOff[j], &QsS[(w * 16 + j * 8) * 64]);
            __syncthreads();   // vmcnt drained before barrier -> LDS filled
            #pragma unroll
            for (int ks = 0; ks < 2; ++ks) {
                const int sp = ((ks * 4 + l4) ^ (l15 & 7)) * 8;
                bf16x8 bq[4];
                #pragma unroll
                for (int s = 0; s < 4; ++s)
                    bq[s] = *(const bf16x8*)&QsS[(s * 16 + l15) * 64 + sp];
                #pragma unroll
                for (int u = 0; u < 8; ++u) {
                    bf16x8 ac = *(const bf16x8*)&CsS[(w * 128 + u * 16 + l15) * 64 + sp];
                    #pragma unroll
                    for (int s = 0; s < 4; ++s)
                        acc[u][s] = __builtin_amdgcn_mfma_f32_16x16x32_bf16(ac, bq[s], acc[u][s], 0, 0, 0);
                }
            }
        }

        // d^2 = |q|^2 + |c|^2 - 2 q.c  -> branchless per-lane register top-5
        #pragma unroll
        for (int u = 0; u < 8; ++u) {
            const int crow = w * 128 + u * 16 + l4 * 4;
            float4 cs4 = *(const float4*)&csq[(size_t)bz * NC + cg0 + crow];
            float csa[4] = {cs4.x, cs4.y, cs4.z, cs4.w};
            #pragma unroll
            for (int s = 0; s < 4; ++s) {
                #pragma unroll
                for (int r = 0; r < 4; ++r) {
                    float v = qsv[s] + csa[r] - 2.0f * acc[u][s][r];
                    ins5b(bv[s], bi[s], v, cg0 + crow + r);
                }
            }
        }
    }

    // wave-level merge across l4 groups (same query columns) via shuffles
    #pragma unroll
    for (int mask = 16; mask <= 32; mask <<= 1) {
        #pragma unroll
        for (int s = 0; s < 4; ++s) {
            float ov[TOPA]; int oi[TOPA];
            #pragma unroll
            for (int j = 0; j < TOPA; ++j) {
                ov[j] = __shfl_xor(bv[s][j], mask, 64);
                oi[j] = __shfl_xor(bi[s][j], mask, 64);
            }
            #pragma unroll
            for (int j = 0; j < TOPA; ++j) insN<TOPA>(bv[s], bi[s], ov[j], oi[j]);
        }
    }
    // cross-wave merge via LDS (l4==0 lanes hold wave-merged lists)
    __syncthreads();
    if (l4 == 0) {
        #pragma unroll
        for (int s = 0; s < 4; ++s) {
            int q = s * 16 + l15;
            #pragma unroll
            for (int j = 0; j < TOPA; ++j) {
                MV[(q * 4 + w) * TOPA + j] = bv[s][j];
                MI[(q * 4 + w) * TOPA + j] = bi[s][j];
            }
        }
    }
    __syncthreads();
    if (t < QT) {
        float mv[TOPA]; int mi[TOPA];
        #pragma unroll
        for (int j = 0; j < TOPA; ++j) { mv[j] = FLT_MAX; mi[j] = 0x7fffffff; }
        for (int l = 0; l < 4; ++l)
            #pragma unroll
            for (int j = 0; j < TOPA; ++j)
                insN<TOPA>(mv, mi, MV[(t * 4 + l) * TOPA + j], MI[(t * 4 + l) * TOPA + j]);
        size_t base = (((size_t)qg0 + t) * CSPLIT + csplit) * TOPA;
        #pragma unroll
        for (int j = 0; j < TOPA; ++j) pi[base + j] = mi[j];
    }
}

// ---- Kernel 5: fp64 exact refine of 40 candidates per query -> top-5, sqrt, outputs ----
__global__ __launch_bounds__(256) void refine_kernel(const double* __restrict__ P64,
                                                     const int* __restrict__ invperm,
                                                     const float* __restrict__ C,
                                                     const int*   __restrict__ pi,
                                                     float* __restrict__ out)
{
    __shared__ double pS[D_DIM];   // 8 KB staged P-row
    __shared__ double dvs[CAND];
    __shared__ int    dis[CAND];
    const int q    = blockIdx.x;                      // true row
    const int pq   = (q & ~15) | invperm[q & 15];     // physical row (P64, Pbf, pi)
    const int bz   = q >> 10;
    const int t    = threadIdx.x;
    const int wave = t >> 6;
    const int lane = t & 63;
    const double* p = P64 + (size_t)pq * D_DIM;

    #pragma unroll
    for (int j = 0; j < D_DIM / 256; ++j) pS[t + j * 256] = p[t + j * 256];
    __syncthreads();

    for (int k = wave; k < CAND; k += 4) {
        int ci = pi[(size_t)pq * CAND + k];
        const float* c = C + ((size_t)bz * NC + ci) * D_DIM;
        double s = 0.0;
        #pragma unroll
        for (int j = 0; j < 16; ++j) {
            int d = lane + 64 * j;
            double diff = pS[d] - (double)c[d];
            s = fma(diff, diff, s);
        }
        #pragma unroll
        for (int off = 32; off; off >>= 1) s += __shfl_down(s, off, 64);
        if (lane == 0) { dvs[k] = s; dis[k] = ci; }
    }
    __syncthreads();
    if (t == 0) {
        double bv[TOPN]; int bi[TOPN];
        #pragma unroll
        for (int j = 0; j < TOPN; ++j) { bv[j] = DBL_MAX; bi[j] = 0x7fffffff; }
        for (int k = 0; k < CAND; ++k)
            topk_insert<TOPN,double>(bv, bi, dvs[k], dis[k]);
        #pragma unroll
        for (int j = 0; j < TOPN; ++j) {
            out[(size_t)q * TOPN + j] = (float)sqrt(bv[j]);
            out[(size_t)B_DIM * NQ * TOPN + (size_t)q * TOPN + j] = (float)bi[j];
        }
    }
}

extern "C" void kernel_launch(void* const* d_in, const int* in_sizes, int n_in,
                              void* d_out, int out_size, void* d_ws, size_t ws_size,
                              hipStream_t stream) {
    const float* Q    = (const float*)d_in[0];
    const float* C    = (const float*)d_in[1];
    const float* W    = (const float*)d_in[2];
    const float* bias = (const float*)d_in[3];
    float* out = (float*)d_out;

    char* ws = (char*)d_ws;
    double*         P64 = (double*)ws;                                       // 32 MB
    unsigned short* Pbf = (unsigned short*)(ws + (size_t)32 * 1024 * 1024);  //  8 MB
    unsigned short* Cbf = (unsigned short*)(ws + (size_t)40 * 1024 * 1024);  // 128 MB
    float*          qsq = (float*)(ws + (size_t)168 * 1024 * 1024);          // 16 KB
    float*          csq = qsq + 4096;                                        // 256 KB
    int*            pi  = (int*)(csq + 65536);                               // 655 KB
    int*            ivp = pi + (size_t)B_DIM * NQ * CAND;                    // 64 B
    // total ~170 MB of workspace

    hipMemsetAsync(qsq, 0, (size_t)B_DIM * NQ * sizeof(float), stream);  // qsq accumulated by atomics
    proj_packc_kernel<<<PROJ_BLKS + (B_DIM * NC) / 4, 256, 0, stream>>>(Q, W, bias, C, P64, Pbf, qsq, Cbf, csq);
    perm_detect_kernel<<<1, 256, 0, stream>>>(Q, W, bias, P64, ivp);
    dist_mfma_kernel<<<dim3(CSPLIT, NQ / QT, B_DIM), 256, 0, stream>>>(Pbf, Cbf, qsq, csq, pi);
    refine_kernel<<<B_DIM * NQ, 256, 0, stream>>>(P64, ivp, C, pi, out);
}